// Round 2
// baseline (206.030 us; speedup 1.0000x reference)
//
#include <hip/hip_runtime.h>
#include <math.h>

#define NRAYS 2048
#define TOT   128
#define INDS  16
#define HID   64
#define EPSF  1e-8f
#define MTOT  (NRAYS*TOT)
#define NTAB  128
#define POOL_GRID 2048

typedef float f32x2 __attribute__((ext_vector_type(2)));
typedef float f32x4 __attribute__((ext_vector_type(4)));

__device__ __forceinline__ float rcp_f(float x) {
    return __builtin_amdgcn_rcpf(x);   // v_rcp_f32, ~1 ulp; tolerance is 0.0625
}
__device__ __forceinline__ float softplus_f(float x) {
    return fmaxf(x, 0.0f) + __logf(1.0f + __expf(-fabsf(x)));
}
__device__ __forceinline__ float sigmoid_f(float x) {
    return rcp_f(1.0f + __expf(-x));
}
__device__ __forceinline__ float tanh_fast(float x) {
    float e2 = __expf(2.0f * x);
    return 1.0f - 2.0f * rcp_f(e2 + 1.0f);
}
__device__ __forceinline__ f32x2 pkmax(f32x2 a, f32x2 b) {
    f32x2 r; r.x = fmaxf(a.x, b.x); r.y = fmaxf(a.y, b.y); return r;
}
__device__ __forceinline__ f32x2 pkfma(f32x2 a, f32x2 b, f32x2 c) {
    return __builtin_elementwise_fma(a, b, c);
}

// z_k = fma(j_k, span/16, fma(span, k/15 - 1/32, nears))
#define CK(i) ((float)(i)*(1.0f/15.0f) - 0.03125f)

#define MAKE_Z(jA, jB, kbase, nears, span)                                    \
    float s16 = (span) * (1.0f/16.0f);                                        \
    f32x2 z01, z23, z45, z67;                                                 \
    z01.x = fmaf((jA).x, s16, fmaf(span, CK((kbase)+0), nears));              \
    z01.y = fmaf((jA).y, s16, fmaf(span, CK((kbase)+1), nears));              \
    z23.x = fmaf((jA).z, s16, fmaf(span, CK((kbase)+2), nears));              \
    z23.y = fmaf((jA).w, s16, fmaf(span, CK((kbase)+3), nears));              \
    z45.x = fmaf((jB).x, s16, fmaf(span, CK((kbase)+4), nears));              \
    z45.y = fmaf((jB).y, s16, fmaf(span, CK((kbase)+5), nears));              \
    z67.x = fmaf((jB).z, s16, fmaf(span, CK((kbase)+6), nears));              \
    z67.y = fmaf((jB).w, s16, fmaf(span, CK((kbase)+7), nears));

// lerp the 4-byte-stride table planes at absolute coordinate zz.
#define TAB_EVAL(zz, mx0, mx1, mx2)                                           \
    {                                                                         \
        float x = ((zz) - ztab0) * invh;                                      \
        x = fminf(fmaxf(x, 0.0f), (float)(NTAB-1) - 1e-3f);                   \
        int i = (int)x; float w = x - (float)i;                               \
        float ta0 = sT0[i], tb0 = sT0[i+1];                                   \
        float ta1 = sT1[i], tb1 = sT1[i+1];                                   \
        float ta2 = sT2[i], tb2 = sT2[i+1];                                   \
        mx0 = fmaxf(mx0, fmaf(w, tb0 - ta0, ta0));                            \
        mx1 = fmaxf(mx1, fmaf(w, tb1 - ta1, ta1));                            \
        mx2 = fmaxf(mx2, fmaf(w, tb2 - ta2, ta2));                            \
    }

__device__ __forceinline__ void env_logv(
    const float* __restrict__ env_map,
    float px, float py, float pz,
    float& v0, float& v1, float& v2)
{
    float theta = atan2f(px, -pz) * (1.0f/3.14159265358979323846f);
    float acv = (fabsf(py) <= 1.0f) ? acosf(py) : 0.0f;  // nan_to_num(arccos)
    float phi = 0.63661977236758134308f * acv - 1.0f;    // 2/pi
    float ixf = ((theta + 1.0f)*256.0f - 1.0f)*0.5f;
    float iyf = ((phi   + 1.0f)*128.0f - 1.0f)*0.5f;
    float x0f = floorf(ixf), y0f = floorf(iyf);
    float wx = ixf - x0f, wy = iyf - y0f;
    v0 = 0.f; v1 = 0.f; v2 = 0.f;
    auto tap = [&](float xc, float yc, float w) {
        if (xc >= 0.0f && xc < 256.0f && yc >= 0.0f && yc < 128.0f) {
            int xi = (int)xc, yi = (int)yc;
            const float* e = env_map + yi*256 + xi;
            v0 += w * e[0];
            v1 += w * e[128*256];
            v2 += w * e[2*128*256];
        }
    };
    tap(x0f,      y0f,      (1.0f-wx)*(1.0f-wy));
    tap(x0f+1.0f, y0f,      wx*(1.0f-wy));
    tap(x0f,      y0f+1.0f, (1.0f-wx)*wy);
    tap(x0f+1.0f, y0f+1.0f, wx*wy);
}

// 256 threads/block = 1 ray; lane pair (2s,2s+1) shares sub-ray s.
// r11: block-uniform density table. r12: non-scattered depth-1 reuses table.
// r13: scattered pool team-of-4. r14: scalar table planes. r15: rcp_f,
// analytic depth-1 roots, jitter plane-1 prefetch.
// NEW (r16): scattered pool is exported to a GLOBAL list and processed by
// a second, grid-strided kernel (perfect load balance). The grid exactly
// fills the machine (8192 waves), so kernel1's runtime = slowest block;
// OccupancyPercent=41% showed a huge imbalance tail dominated by the
// variable-size pool phase (npool ~30-60 of 64 teams -> idle teams +
// block variance). Overflow (small ws) falls back to the old local loop.
__global__ __launch_bounds__(256)
void render_kernel(const float* __restrict__ rays_o,
                   const float* __restrict__ rays_d,
                   const float* __restrict__ env_map,
                   const float* __restrict__ Wd1,
                   const float* __restrict__ Wd2,
                   const float* __restrict__ Wf1,
                   const float* __restrict__ Ws,
                   const float* __restrict__ Wdir,
                   const float* __restrict__ Wrho,
                   const float* __restrict__ jitter,
                   const float* __restrict__ u_t,
                   const float* __restrict__ u_scatter,
                   const int*   __restrict__ channel,
                   unsigned int* __restrict__ g_count,
                   float4* __restrict__ e0g,
                   float4* __restrict__ e1g,
                   float2* __restrict__ e2g,
                   int cap,
                   float* __restrict__ out)
{
    const int ray  = blockIdx.x;
    const int tid  = threadIdx.x;
    const int s    = tid >> 1;
    const int half = tid & 1;
    const int m    = ray * TOT + s;
    const int kbase = half * 8;

    __shared__ f32x4 sAB[HID];     // {A,A,B,B}
    __shared__ f32x4 sW01[HID];    // {w20,w20,w21,w21}
    __shared__ f32x2 sW2[HID];     // {w22,w22}
    __shared__ f32x4 sPW[HID];     // {pw1x,pw1y,pw1z,0}
    __shared__ f32x4 sM0[HID];     // {P, Q, ws0, ws1}
    __shared__ f32x4 sM1[HID];     // {ws2, wd0, wd1, wd2}
    __shared__ f32x4 sM2[HID];     // {wr0, wr1, wr2, 0}
    __shared__ float sT0[NTAB];    // density table, channel 0 (4B stride)
    __shared__ float sT1[NTAB];
    __shared__ float sT2[NTAB];
    __shared__ f32x4 sP0[TOT];     // pool: {ox,oy,oz,dx}
    __shared__ f32x4 sP1[TOT];     // pool: {dy,dz,thr0,thr1}
    __shared__ f32x2 sP2[TOT];     // pool: {thr2, (float)m}
    __shared__ float sEnvE[3];     // exp(env) at block-uniform exit point
    __shared__ int   sCnt;
    __shared__ int   sGbase;
    __shared__ float sred[4][3];

    // ---- prefetch per-thread globals (both jitter planes up front) ----
    const float4* j0p = (const float4*)(jitter + (size_t)m*INDS + kbase);
    float4 j0A = j0p[0], j0B = j0p[1];
    const float4* j1p = (const float4*)(jitter + ((size_t)MTOT + m)*INDS + kbase);
    float4 j1A = j1p[0], j1B = j1p[1];
    int   ch = channel[m];
    float ut = u_t[m];
    float us = u_scatter[m];

    float ox = rays_o[ray*3+0], oy = rays_o[ray*3+1], oz = rays_o[ray*3+2];
    float dx = rays_d[ray*3+0], dy = rays_d[ray*3+1], dz = rays_d[ray*3+2];

    if (tid == 0) sCnt = 0;
    // ---- per-block weight tables ----
    if (tid < HID) {
        const float INV2PI = 0.15915494309189535f;
        float w1x = Wd1[tid], w1y = Wd1[HID+tid], w1z = Wd1[2*HID+tid];
        float pw1x = w1x*INV2PI, pw1y = w1y*INV2PI, pw1z = w1z*INV2PI;
        float A = ox*pw1x + oy*pw1y + oz*pw1z;
        float B = dx*pw1x + dy*pw1y + dz*pw1z;
        float w20 = Wd2[3*tid], w21 = Wd2[3*tid+1], w22 = Wd2[3*tid+2];
        sAB[tid]  = (f32x4){A, A, B, B};
        sW01[tid] = (f32x4){w20, w20, w21, w21};
        sW2[tid]  = (f32x2){w22, w22};
        sPW[tid]  = (f32x4){pw1x, pw1y, pw1z, 0.0f};
        float f0 = Wf1[tid],       f1 = Wf1[HID+tid],   f2 = Wf1[2*HID+tid];
        float f3 = Wf1[3*HID+tid], f4 = Wf1[4*HID+tid], f5 = Wf1[5*HID+tid];
        float P = ox*f0 + oy*f1 + oz*f2 + dx*f3 + dy*f4 + dz*f5;
        float Q = dx*f0 + dy*f1 + dz*f2;
        sM0[tid] = (f32x4){P, Q, Ws[3*tid], Ws[3*tid+1]};
        sM1[tid] = (f32x4){Ws[3*tid+2], Wdir[3*tid], Wdir[3*tid+1], Wdir[3*tid+2]};
        sM2[tid] = (f32x4){Wrho[3*tid], Wrho[3*tid+1], Wrho[3*tid+2], 0.0f};
    }
    __syncthreads();

    // ---- block-uniform depth-0 geometry + density table + env ----
    float a0g = dx*dx + dy*dy + dz*dz;
    float b0g = 2.0f*(dx*ox + dy*oy + dz*oz);
    float c0g = (ox*ox + oy*oy + oz*oz) - 1.0f;
    float delta0 = b0g*b0g - 4.0f*a0g*c0g;
    bool alive = (delta0 > 0.0f);   // block-uniform

    float nears = 0.f, fars = 0.f, span = 0.f, ztab0 = 0.f, invh = 0.f;
    if (alive) {
        float sq = sqrtf(delta0);
        float inv2a = rcp_f(a0g + a0g);
        nears = fmaxf((-b0g - sq) * inv2a, 0.001f);
        fars  = fmaxf((-b0g + sq) * inv2a, 0.001f);
        span  = fars - nears;
        ztab0 = fmaf(-span, 0.03125f, nears);
        float width = span * 1.0625f;
        float hstep = width * (1.0f/(NTAB-1));
        invh = (float)(NTAB-1) * rcp_f(width);
        int p = tid >> 1;
        float zp = fmaf((float)p, hstep, ztab0);
        float f0 = 0.f, f1 = 0.f, f2 = 0.f;
        const int jb = half * 32;
        #pragma unroll 4
        for (int j = jb; j < jb + 32; ++j) {
            f32x4 ab  = sAB[j];
            f32x4 w01 = sW01[j];
            f32x2 w2  = sW2[j];
            float hv = __builtin_amdgcn_sinf(fmaf(zp, ab.z, ab.x));
            f0 = fmaf(hv, w01.x, f0);
            f1 = fmaf(hv, w01.z, f1);
            f2 = fmaf(hv, w2.x, f2);
        }
        f0 += __shfl_xor(f0, 1, 64);
        f1 += __shfl_xor(f1, 1, 64);
        f2 += __shfl_xor(f2, 1, 64);
        if (half == 0) { sT0[p] = f0; sT1[p] = f1; sT2[p] = f2; }
        if (tid == 0) {
            float v0,v1,v2;
            env_logv(env_map, fmaf(dx,fars,ox), fmaf(dy,fars,oy), fmaf(dz,fars,oz),
                     v0,v1,v2);
            sEnvE[0] = __expf(v0); sEnvE[1] = __expf(v1); sEnvE[2] = __expf(v2);
        }
    }
    __syncthreads();

    float thr0 = 1.f, thr1 = 1.f, thr2 = 1.f;
    float rgb0 = 0.f, rgb1 = 0.f, rgb2 = 0.f;
    bool  tab_d1 = false;
    float tadv = 0.f;

    // ================= depth 0 =================
    if (alive) {
        MAKE_Z(j0A, j0B, kbase, nears, span)
        float mx0 = -1e30f, mx1 = -1e30f, mx2 = -1e30f;
        TAB_EVAL(z01.x, mx0,mx1,mx2) TAB_EVAL(z01.y, mx0,mx1,mx2)
        TAB_EVAL(z23.x, mx0,mx1,mx2) TAB_EVAL(z23.y, mx0,mx1,mx2)
        TAB_EVAL(z45.x, mx0,mx1,mx2) TAB_EVAL(z45.y, mx0,mx1,mx2)
        TAB_EVAL(z67.x, mx0,mx1,mx2) TAB_EVAL(z67.y, mx0,mx1,mx2)
        mx0 = fmaxf(mx0, __shfl_xor(mx0, 1, 64));
        mx1 = fmaxf(mx1, __shfl_xor(mx1, 1, 64));
        mx2 = fmaxf(mx2, __shfl_xor(mx2, 1, 64));

        float maj0 = fmaxf(softplus_f(mx0), 0.001f);
        float maj1 = fmaxf(softplus_f(mx1), 0.001f);
        float maj2 = fmaxf(softplus_f(mx2), 0.001f);
        float mmax = fmaxf(fmaxf(maj0, maj1), maj2);

        float maj = (ch == 0) ? maj0 : ((ch == 1) ? maj1 : maj2);
        float t   = fmaf(-__logf(1.0f - ut), rcp_f(maj), nears);

        if (t >= fars) {
            float im   = rcp_f(mmax + EPSF);
            float den0 = fmaf(__expf(-maj0*span), im, EPSF);
            float den1 = fmaf(__expf(-maj1*span), im, EPSF);
            float den2 = fmaf(__expf(-maj2*span), im, EPSF);
            float idm = 3.0f * rcp_f(den0+den1+den2);
            rgb0 = den0*idm*sEnvE[0];
            rgb1 = den1*idm*sEnvE[1];
            rgb2 = den2*idm*sEnvE[2];
        } else {
            float tn  = t - nears;
            float imm = rcp_f(mmax);
            float tr0 = __expf(-maj0*tn) * imm;
            float tr1 = __expf(-maj1*tn) * imm;
            float tr2 = __expf(-maj2*tn) * imm;
            float i2m = 3.0f * rcp_f(maj0*tr0 + maj1*tr1 + maj2*tr2);
            thr0 = tr0 * i2m;   // thr was 1
            thr1 = tr1 * i2m;
            thr2 = tr2 * i2m;
            ox = fmaf(dx, t, ox); oy = fmaf(dy, t, oy); oz = fmaf(dz, t, oz);

            // material MLP (DS-only; pre = P + t*Q)
            float st0=0.f, st1=0.f, st2=0.f;
            float dn0=0.f, dn1=0.f, dn2v=0.f;
            float rh0=0.f, rh1=0.f, rh2=0.f;
            const int j0 = half * 32;
            #pragma unroll 2
            for (int j = j0; j < j0 + 32; ++j) {
                f32x4 q0 = sM0[j];
                f32x4 q1 = sM1[j];
                f32x4 q2 = sM2[j];
                float pre = fmaf(t, q0.y, q0.x);
                float f = tanh_fast(pre);
                st0  = fmaf(f, q0.z, st0);
                st1  = fmaf(f, q0.w, st1);
                st2  = fmaf(f, q1.x, st2);
                dn0  = fmaf(f, q1.y, dn0);
                dn1  = fmaf(f, q1.z, dn1);
                dn2v = fmaf(f, q1.w, dn2v);
                rh0  = fmaf(f, q2.x, rh0);
                rh1  = fmaf(f, q2.y, rh1);
                rh2  = fmaf(f, q2.z, rh2);
            }
            st0  += __shfl_xor(st0, 1, 64);
            st1  += __shfl_xor(st1, 1, 64);
            st2  += __shfl_xor(st2, 1, 64);
            dn0  += __shfl_xor(dn0, 1, 64);
            dn1  += __shfl_xor(dn1, 1, 64);
            dn2v += __shfl_xor(dn2v, 1, 64);
            rh0  += __shfl_xor(rh0, 1, 64);
            rh1  += __shfl_xor(rh1, 1, 64);
            rh2  += __shfl_xor(rh2, 1, 64);

            float stch = (ch == 0) ? st0 : ((ch == 1) ? st1 : st2);
            float sp = fminf(softplus_f(stch) * rcp_f(maj), 1.0f);
            if (us < sp) {
                float inr = rcp_f(sqrtf(dn0*dn0 + dn1*dn1 + dn2v*dn2v) + EPSF);
                float ndx = dn0*inr, ndy = dn1*inr, ndz = dn2v*inr;
                float isp = rcp_f(sp + EPSF);
                float t0 = thr0 * isp * sigmoid_f(rh0);
                float t1 = thr1 * isp * sigmoid_f(rh1);
                float t2 = thr2 * isp * sigmoid_f(rh2);
                if (half == 0) {
                    int sl = atomicAdd(&sCnt, 1);
                    sP0[sl] = (f32x4){ox, oy, oz, ndx};
                    sP1[sl] = (f32x4){ndy, ndz, t0, t1};
                    sP2[sl] = (f32x2){t2, (float)m};
                }
            } else {
                float iv = rcp_f(1.0f - sp + EPSF);
                thr0 *= iv; thr1 *= iv; thr2 *= iv;
                tab_d1 = true;
                tadv = t;
            }
        }
    }
    __syncthreads();
    int npool = sCnt;

    // ---- export pool to global list (one atomic per block) ----
    if (tid == 0) {
        sGbase = (cap > 0 && npool > 0)
               ? (int)atomicAdd(g_count, (unsigned int)npool) : 0;
    }
    __syncthreads();
    int gbase = sGbase;
    for (int i = tid; i < npool; i += 256) {
        int gi = gbase + i;
        if (gi < cap) {
            f32x4 a = sP0[i]; f32x4 b = sP1[i]; f32x2 c = sP2[i];
            e0g[gi] = make_float4(a.x, a.y, a.z, a.w);
            e1g[gi] = make_float4(b.x, b.y, b.z, b.w);
            e2g[gi] = make_float2(c.x, c.y);
        }
    }
    // entries that didn't fit in ws are processed locally below
    int qstart = npool;
    if (cap > 0) {
        int fit = cap - gbase;
        if (fit < 0) fit = 0;
        if (fit > npool) fit = npool;
        qstart = fit;
    } else {
        qstart = 0;
    }

    // ===== depth 1, non-scattered: same line as depth 0, roots shift by -t
    if (tab_d1) {
        float fars1 = fmaxf(fars - tadv, 0.001f);
        float span1 = fars1 - 0.001f;
        float n1    = tadv + 0.001f;
        MAKE_Z(j1A, j1B, kbase, n1, span1)
        float mx0 = -1e30f, mx1 = -1e30f, mx2 = -1e30f;
        TAB_EVAL(z01.x, mx0,mx1,mx2) TAB_EVAL(z01.y, mx0,mx1,mx2)
        TAB_EVAL(z23.x, mx0,mx1,mx2) TAB_EVAL(z23.y, mx0,mx1,mx2)
        TAB_EVAL(z45.x, mx0,mx1,mx2) TAB_EVAL(z45.y, mx0,mx1,mx2)
        TAB_EVAL(z67.x, mx0,mx1,mx2) TAB_EVAL(z67.y, mx0,mx1,mx2)
        mx0 = fmaxf(mx0, __shfl_xor(mx0, 1, 64));
        mx1 = fmaxf(mx1, __shfl_xor(mx1, 1, 64));
        mx2 = fmaxf(mx2, __shfl_xor(mx2, 1, 64));

        float maj0 = fmaxf(softplus_f(mx0), 0.001f);
        float maj1 = fmaxf(softplus_f(mx1), 0.001f);
        float maj2 = fmaxf(softplus_f(mx2), 0.001f);
        float mmax = fmaxf(fmaxf(maj0, maj1), maj2);

        float im   = rcp_f(mmax + EPSF);
        float den0 = fmaf(__expf(-maj0*span1), im, EPSF);
        float den1 = fmaf(__expf(-maj1*span1), im, EPSF);
        float den2 = fmaf(__expf(-maj2*span1), im, EPSF);
        float idm = 3.0f * rcp_f(den0+den1+den2);
        rgb0 += thr0 * den0*idm*sEnvE[0];
        rgb1 += thr1 * den1*idm*sEnvE[1];
        rgb2 += thr2 * den2*idm*sEnvE[2];
    }

    // ===== depth 1, scattered OVERFLOW only (normally empty) =====
    {
        const int qlane = tid & 3;          // sample quarter
        const int kq    = qlane * 4;
        const float kqf = (float)kq;
        for (int q = qstart + (tid >> 2); q < npool; q += 64) {
            f32x4 p0 = sP0[q];
            f32x4 p1 = sP1[q];
            f32x2 p2 = sP2[q];
            float pox = p0.x, poy = p0.y, poz = p0.z;
            float pdx = p0.w, pdy = p1.x, pdz = p1.y;
            float pt0 = p1.z, pt1 = p1.w, pt2 = p2.x;
            int   mm  = (int)p2.y;

            float a1 = pdx*pdx + pdy*pdy + pdz*pdz;
            float b1 = 2.0f*(pdx*pox + pdy*poy + pdz*poz);
            float c1 = (pox*pox + poy*poy + poz*poz) - 1.0f;
            float delta1 = b1*b1 - 4.0f*a1*c1;
            if (delta1 > 0.0f) {
                const float4* jp = (const float4*)(jitter + ((size_t)MTOT + mm)*INDS + kq);
                float4 jq = jp[0];
                float sq1    = sqrtf(delta1);
                float inv2a1 = rcp_f(a1 + a1);
                float nears1 = fmaxf((-b1 - sq1) * inv2a1, 0.001f);
                float fars1  = fmaxf((-b1 + sq1) * inv2a1, 0.001f);
                float span1  = fars1 - nears1;
                float s16q   = span1 * (1.0f/16.0f);
                f32x2 zA, zB;
                zA.x = fmaf(jq.x, s16q, fmaf(span1, (kqf+0.0f)*(1.0f/15.0f) - 0.03125f, nears1));
                zA.y = fmaf(jq.y, s16q, fmaf(span1, (kqf+1.0f)*(1.0f/15.0f) - 0.03125f, nears1));
                zB.x = fmaf(jq.z, s16q, fmaf(span1, (kqf+2.0f)*(1.0f/15.0f) - 0.03125f, nears1));
                zB.y = fmaf(jq.w, s16q, fmaf(span1, (kqf+3.0f)*(1.0f/15.0f) - 0.03125f, nears1));

                f32x2 a0A = {0.f,0.f}, a0B = {0.f,0.f};
                f32x2 a1A = {0.f,0.f}, a1B = {0.f,0.f};
                f32x2 a2A = {0.f,0.f}, a2B = {0.f,0.f};
                #pragma unroll 2
                for (int j = 0; j < HID; ++j) {
                    f32x4 pw  = sPW[j];
                    f32x4 w01 = sW01[j];
                    f32x2 w2  = sW2[j];
                    float A = fmaf(pox, pw.x, fmaf(poy, pw.y, poz*pw.z));
                    float B = fmaf(pdx, pw.x, fmaf(pdy, pw.y, pdz*pw.z));
                    f32x2 A2 = {A, A}, B2 = {B, B};
                    f32x2 gA = pkfma(zA, B2, A2);
                    f32x2 gB = pkfma(zB, B2, A2);
                    f32x2 hA, hB;
                    hA.x = __builtin_amdgcn_sinf(gA.x); hA.y = __builtin_amdgcn_sinf(gA.y);
                    hB.x = __builtin_amdgcn_sinf(gB.x); hB.y = __builtin_amdgcn_sinf(gB.y);
                    f32x2 W0 = {w01.x, w01.y}, W1 = {w01.z, w01.w};
                    a0A = pkfma(hA, W0, a0A); a0B = pkfma(hB, W0, a0B);
                    a1A = pkfma(hA, W1, a1A); a1B = pkfma(hB, W1, a1B);
                    a2A = pkfma(hA, w2, a2A); a2B = pkfma(hB, w2, a2B);
                }
                f32x2 pm0 = pkmax(a0A, a0B);
                f32x2 pm1 = pkmax(a1A, a1B);
                f32x2 pm2 = pkmax(a2A, a2B);
                float mx0 = fmaxf(pm0.x, pm0.y);
                float mx1 = fmaxf(pm1.x, pm1.y);
                float mx2 = fmaxf(pm2.x, pm2.y);
                mx0 = fmaxf(mx0, __shfl_xor(mx0, 1, 64));
                mx1 = fmaxf(mx1, __shfl_xor(mx1, 1, 64));
                mx2 = fmaxf(mx2, __shfl_xor(mx2, 1, 64));
                mx0 = fmaxf(mx0, __shfl_xor(mx0, 2, 64));
                mx1 = fmaxf(mx1, __shfl_xor(mx1, 2, 64));
                mx2 = fmaxf(mx2, __shfl_xor(mx2, 2, 64));

                float maj0 = fmaxf(softplus_f(mx0), 0.001f);
                float maj1 = fmaxf(softplus_f(mx1), 0.001f);
                float maj2 = fmaxf(softplus_f(mx2), 0.001f);
                float mmax = fmaxf(fmaxf(maj0, maj1), maj2);

                float im   = rcp_f(mmax + EPSF);
                float den0 = fmaf(__expf(-maj0*span1), im, EPSF);
                float den1 = fmaf(__expf(-maj1*span1), im, EPSF);
                float den2 = fmaf(__expf(-maj2*span1), im, EPSF);
                float idm = 3.0f * rcp_f(den0+den1+den2);
                float v0,v1,v2;
                env_logv(env_map, fmaf(pdx,fars1,pox), fmaf(pdy,fars1,poy),
                         fmaf(pdz,fars1,poz), v0,v1,v2);
                if (qlane < 2) {
                    rgb0 += pt0 * den0*idm*__expf(v0);
                    rgb1 += pt1 * den1*idm*__expf(v1);
                    rgb2 += pt2 * den2*idm*__expf(v2);
                }
            }
        }
    }

    // ---- reduction: each sub-ray counted x2 -> sum/256 == mean/128 ----
    float r0 = rgb0, r1 = rgb1, r2 = rgb2;
    #pragma unroll
    for (int off = 32; off > 0; off >>= 1) {
        r0 += __shfl_down(r0, off, 64);
        r1 += __shfl_down(r1, off, 64);
        r2 += __shfl_down(r2, off, 64);
    }
    int wave = tid >> 6;
    if ((tid & 63) == 0) {
        sred[wave][0] = r0; sred[wave][1] = r1; sred[wave][2] = r2;
    }
    __syncthreads();
    if (tid == 0) {
        out[ray*3+0] = (sred[0][0]+sred[1][0]+sred[2][0]+sred[3][0]) * (1.0f/256.0f);
        out[ray*3+1] = (sred[0][1]+sred[1][1]+sred[2][1]+sred[3][1]) * (1.0f/256.0f);
        out[ray*3+2] = (sred[0][2]+sred[1][2]+sred[2][2]+sred[3][2]) * (1.0f/256.0f);
    }
}

// Grid-strided, globally balanced scattered-pool pass. Teams of 4 lanes,
// one entry per team per stride step. Weights are ray-independent.
// Contribution per entry = pt*den*idm*exp(env) / 128 (matches the
// 2x-counted /256 accounting of the in-block path), atomicAdd'ed to out.
__global__ __launch_bounds__(256)
void pool_kernel(const float* __restrict__ env_map,
                 const float* __restrict__ Wd1,
                 const float* __restrict__ Wd2,
                 const float* __restrict__ jitter,
                 const unsigned int* __restrict__ g_count,
                 const float4* __restrict__ e0g,
                 const float4* __restrict__ e1g,
                 const float2* __restrict__ e2g,
                 int cap,
                 float* __restrict__ out)
{
    __shared__ f32x4 sPW4[HID];   // {pwx, pwy, pwz, w20}
    __shared__ f32x2 sW22[HID];   // {w21, w22}
    const int tid = threadIdx.x;
    if (tid < HID) {
        const float INV2PI = 0.15915494309189535f;
        sPW4[tid] = (f32x4){Wd1[tid]*INV2PI, Wd1[HID+tid]*INV2PI,
                            Wd1[2*HID+tid]*INV2PI, Wd2[3*tid]};
        sW22[tid] = (f32x2){Wd2[3*tid+1], Wd2[3*tid+2]};
    }
    __syncthreads();

    int count = (int)*g_count;
    if (count > cap) count = cap;

    const int qlane = tid & 3;
    const int kq    = qlane * 4;
    const float kqf = (float)kq;

    for (int idx = blockIdx.x*64 + (tid >> 2); idx < count; idx += gridDim.x*64) {
        float4 p0 = e0g[idx];
        float4 p1 = e1g[idx];
        float2 p2 = e2g[idx];
        float pox = p0.x, poy = p0.y, poz = p0.z;
        float pdx = p0.w, pdy = p1.x, pdz = p1.y;
        float pt0 = p1.z, pt1 = p1.w, pt2 = p2.x;
        int   mm  = (int)p2.y;

        float a1 = pdx*pdx + pdy*pdy + pdz*pdz;
        float b1 = 2.0f*(pdx*pox + pdy*poy + pdz*poz);
        float c1 = (pox*pox + poy*poy + poz*poz) - 1.0f;
        float delta1 = b1*b1 - 4.0f*a1*c1;
        if (delta1 > 0.0f) {   // origin inside sphere -> essentially always true
            const float4* jp = (const float4*)(jitter + ((size_t)MTOT + mm)*INDS + kq);
            float4 jq = jp[0];
            float sq1    = sqrtf(delta1);
            float inv2a1 = rcp_f(a1 + a1);
            float nears1 = fmaxf((-b1 - sq1) * inv2a1, 0.001f);
            float fars1  = fmaxf((-b1 + sq1) * inv2a1, 0.001f);
            float span1  = fars1 - nears1;
            float s16q   = span1 * (1.0f/16.0f);
            f32x2 zA, zB;
            zA.x = fmaf(jq.x, s16q, fmaf(span1, (kqf+0.0f)*(1.0f/15.0f) - 0.03125f, nears1));
            zA.y = fmaf(jq.y, s16q, fmaf(span1, (kqf+1.0f)*(1.0f/15.0f) - 0.03125f, nears1));
            zB.x = fmaf(jq.z, s16q, fmaf(span1, (kqf+2.0f)*(1.0f/15.0f) - 0.03125f, nears1));
            zB.y = fmaf(jq.w, s16q, fmaf(span1, (kqf+3.0f)*(1.0f/15.0f) - 0.03125f, nears1));

            f32x2 a0A = {0.f,0.f}, a0B = {0.f,0.f};
            f32x2 a1A = {0.f,0.f}, a1B = {0.f,0.f};
            f32x2 a2A = {0.f,0.f}, a2B = {0.f,0.f};
            #pragma unroll 2
            for (int j = 0; j < HID; ++j) {
                f32x4 pw  = sPW4[j];
                f32x2 w22 = sW22[j];
                float A = fmaf(pox, pw.x, fmaf(poy, pw.y, poz*pw.z));
                float B = fmaf(pdx, pw.x, fmaf(pdy, pw.y, pdz*pw.z));
                f32x2 A2 = {A, A}, B2 = {B, B};
                f32x2 gA = pkfma(zA, B2, A2);
                f32x2 gB = pkfma(zB, B2, A2);
                f32x2 hA, hB;
                hA.x = __builtin_amdgcn_sinf(gA.x); hA.y = __builtin_amdgcn_sinf(gA.y);
                hB.x = __builtin_amdgcn_sinf(gB.x); hB.y = __builtin_amdgcn_sinf(gB.y);
                f32x2 W0 = {pw.w, pw.w}, W1 = {w22.x, w22.x}, W2v = {w22.y, w22.y};
                a0A = pkfma(hA, W0, a0A); a0B = pkfma(hB, W0, a0B);
                a1A = pkfma(hA, W1, a1A); a1B = pkfma(hB, W1, a1B);
                a2A = pkfma(hA, W2v, a2A); a2B = pkfma(hB, W2v, a2B);
            }
            f32x2 pm0 = pkmax(a0A, a0B);
            f32x2 pm1 = pkmax(a1A, a1B);
            f32x2 pm2 = pkmax(a2A, a2B);
            float mx0 = fmaxf(pm0.x, pm0.y);
            float mx1 = fmaxf(pm1.x, pm1.y);
            float mx2 = fmaxf(pm2.x, pm2.y);
            mx0 = fmaxf(mx0, __shfl_xor(mx0, 1, 64));
            mx1 = fmaxf(mx1, __shfl_xor(mx1, 1, 64));
            mx2 = fmaxf(mx2, __shfl_xor(mx2, 1, 64));
            mx0 = fmaxf(mx0, __shfl_xor(mx0, 2, 64));
            mx1 = fmaxf(mx1, __shfl_xor(mx1, 2, 64));
            mx2 = fmaxf(mx2, __shfl_xor(mx2, 2, 64));

            float maj0 = fmaxf(softplus_f(mx0), 0.001f);
            float maj1 = fmaxf(softplus_f(mx1), 0.001f);
            float maj2 = fmaxf(softplus_f(mx2), 0.001f);
            float mmax = fmaxf(fmaxf(maj0, maj1), maj2);

            float im   = rcp_f(mmax + EPSF);
            float den0 = fmaf(__expf(-maj0*span1), im, EPSF);
            float den1 = fmaf(__expf(-maj1*span1), im, EPSF);
            float den2 = fmaf(__expf(-maj2*span1), im, EPSF);
            float idm = 3.0f * rcp_f(den0+den1+den2);
            float v0,v1,v2;
            env_logv(env_map, fmaf(pdx,fars1,pox), fmaf(pdy,fars1,poy),
                     fmaf(pdz,fars1,poz), v0,v1,v2);
            if (qlane == 0) {
                int ray = mm >> 7;   // mm / TOT
                atomicAdd(&out[ray*3+0], pt0*den0*idm*__expf(v0)*(1.0f/128.0f));
                atomicAdd(&out[ray*3+1], pt1*den1*idm*__expf(v1)*(1.0f/128.0f));
                atomicAdd(&out[ray*3+2], pt2*den2*idm*__expf(v2)*(1.0f/128.0f));
            }
        }
    }
}

extern "C" void kernel_launch(void* const* d_in, const int* in_sizes, int n_in,
                              void* d_out, int out_size, void* d_ws, size_t ws_size,
                              hipStream_t stream) {
    const float* rays_o    = (const float*)d_in[0];
    const float* rays_d    = (const float*)d_in[1];
    const float* env_map   = (const float*)d_in[2];
    const float* Wd1       = (const float*)d_in[3];
    const float* Wd2       = (const float*)d_in[4];
    const float* Wf1       = (const float*)d_in[5];
    const float* Ws        = (const float*)d_in[6];
    const float* Wdir      = (const float*)d_in[7];
    const float* Wrho      = (const float*)d_in[8];
    const float* jitter    = (const float*)d_in[9];
    const float* u_t       = (const float*)d_in[10];
    const float* u_scatter = (const float*)d_in[11];
    const int*   channel   = (const int*)d_in[12];
    float* out = (float*)d_out;

    // workspace layout: [0..4) count | [256 ..) e0 | e1 | e2
    int cap = 0;
    unsigned int* g_count = nullptr;
    float4* e0g = nullptr; float4* e1g = nullptr; float2* e2g = nullptr;
    if (d_ws && ws_size >= 4096) {
        long c = ((long)ws_size - 256) / 40;   // 16+16+8 bytes per entry
        if (c > MTOT) c = MTOT;
        cap = (int)c;
        char* base = (char*)d_ws;
        g_count = (unsigned int*)base;
        e0g = (float4*)(base + 256);
        e1g = (float4*)(base + 256 + (size_t)cap*16);
        e2g = (float2*)(base + 256 + (size_t)cap*32);
    }

    if (cap > 0) {
        hipMemsetAsync(d_ws, 0, 4, stream);
    }

    render_kernel<<<dim3(NRAYS), dim3(256), 0, stream>>>(
        rays_o, rays_d, env_map, Wd1, Wd2, Wf1, Ws, Wdir, Wrho,
        jitter, u_t, u_scatter, channel,
        g_count, e0g, e1g, e2g, cap, out);

    if (cap > 0) {
        pool_kernel<<<dim3(POOL_GRID), dim3(256), 0, stream>>>(
            env_map, Wd1, Wd2, jitter, g_count, e0g, e1g, e2g, cap, out);
    }
}

// Round 3
// 165.606 us; speedup vs baseline: 1.2441x; 1.2441x over previous
//
#include <hip/hip_runtime.h>
#include <math.h>

#define NRAYS 2048
#define TOT   128
#define INDS  16
#define HID   64
#define EPSF  1e-8f
#define MTOT  (NRAYS*TOT)
#define NTAB  128
#define POOL_GRID 2048

typedef float f32x2 __attribute__((ext_vector_type(2)));
typedef float f32x4 __attribute__((ext_vector_type(4)));

__device__ __forceinline__ float rcp_f(float x) {
    return __builtin_amdgcn_rcpf(x);   // v_rcp_f32, ~1 ulp; tolerance is 0.0625
}
__device__ __forceinline__ float softplus_f(float x) {
    return fmaxf(x, 0.0f) + __logf(1.0f + __expf(-fabsf(x)));
}
__device__ __forceinline__ float sigmoid_f(float x) {
    return rcp_f(1.0f + __expf(-x));
}
__device__ __forceinline__ float tanh_fast(float x) {
    float e2 = __expf(2.0f * x);
    return 1.0f - 2.0f * rcp_f(e2 + 1.0f);
}
__device__ __forceinline__ f32x2 pkmax(f32x2 a, f32x2 b) {
    f32x2 r; r.x = fmaxf(a.x, b.x); r.y = fmaxf(a.y, b.y); return r;
}
__device__ __forceinline__ f32x2 pkfma(f32x2 a, f32x2 b, f32x2 c) {
    return __builtin_elementwise_fma(a, b, c);
}

// ---- cheap transcendentals (replace ocml atan2f/acosf: each was a 30-50 op
// sequence incl. an IEEE divide; these are ~16/~8 ops, err <= 7e-5 rad ->
// texel-coord err ~3e-3 -> rgb err ~1e-3, way under 0.0625 tolerance) ----
__device__ __forceinline__ float atan_poly(float r) {
    float r2 = r*r;
    float p = -0.0117212f;
    p = fmaf(p, r2,  0.05265332f);
    p = fmaf(p, r2, -0.11643287f);
    p = fmaf(p, r2,  0.19354346f);
    p = fmaf(p, r2, -0.33262347f);
    p = fmaf(p, r2,  0.99997726f);
    return r * p;
}
__device__ __forceinline__ float atan2_fast(float y, float x) {
    float ay = fabsf(y), ax = fabsf(x);
    float mx = fmaxf(ay, ax), mn = fminf(ay, ax);
    float r  = mn * rcp_f(fmaxf(mx, 1e-30f));
    float t  = atan_poly(r);
    t = (ay > ax) ? (1.57079632679f - t) : t;
    t = (x < 0.0f) ? (3.14159265359f - t) : t;
    return (y < 0.0f) ? -t : t;          // atan2(0,0) -> 0 (matches nan_to_num)
}
__device__ __forceinline__ float acos_fast(float x) {
    // Hastings: acos(|x|) = sqrt(1-|x|)*poly, err <= 6.7e-5 rad
    float ax = fabsf(x);
    float p = -0.0187293f;
    p = fmaf(p, ax,  0.0742610f);
    p = fmaf(p, ax, -0.2121144f);
    p = fmaf(p, ax,  1.5707288f);
    float s = sqrtf(1.0f - ax) * p;
    return (x < 0.0f) ? (3.14159265359f - s) : s;
}

// z_k = fma(j_k, span/16, fma(span, k/15 - 1/32, nears))
#define CK(i) ((float)(i)*(1.0f/15.0f) - 0.03125f)

#define MAKE_Z(jA, jB, kbase, nears, span)                                    \
    float s16 = (span) * (1.0f/16.0f);                                        \
    f32x2 z01, z23, z45, z67;                                                 \
    z01.x = fmaf((jA).x, s16, fmaf(span, CK((kbase)+0), nears));              \
    z01.y = fmaf((jA).y, s16, fmaf(span, CK((kbase)+1), nears));              \
    z23.x = fmaf((jA).z, s16, fmaf(span, CK((kbase)+2), nears));              \
    z23.y = fmaf((jA).w, s16, fmaf(span, CK((kbase)+3), nears));              \
    z45.x = fmaf((jB).x, s16, fmaf(span, CK((kbase)+4), nears));              \
    z45.y = fmaf((jB).y, s16, fmaf(span, CK((kbase)+5), nears));              \
    z67.x = fmaf((jB).z, s16, fmaf(span, CK((kbase)+6), nears));              \
    z67.y = fmaf((jB).w, s16, fmaf(span, CK((kbase)+7), nears));

#define TAB_EVAL(zz, mx0, mx1, mx2)                                           \
    {                                                                         \
        float x = ((zz) - ztab0) * invh;                                      \
        x = fminf(fmaxf(x, 0.0f), (float)(NTAB-1) - 1e-3f);                   \
        int i = (int)x; float w = x - (float)i;                               \
        float ta0 = sT0[i], tb0 = sT0[i+1];                                   \
        float ta1 = sT1[i], tb1 = sT1[i+1];                                   \
        float ta2 = sT2[i], tb2 = sT2[i+1];                                   \
        mx0 = fmaxf(mx0, fmaf(w, tb0 - ta0, ta0));                            \
        mx1 = fmaxf(mx1, fmaf(w, tb1 - ta1, ta1));                            \
        mx2 = fmaxf(mx2, fmaf(w, tb2 - ta2, ta2));                            \
    }

__device__ __forceinline__ void env_logv(
    const float* __restrict__ env_map,
    float px, float py, float pz,
    float& v0, float& v1, float& v2)
{
    float theta = atan2_fast(px, -pz) * (1.0f/3.14159265358979323846f);
    float acv = (fabsf(py) <= 1.0f) ? acos_fast(py) : 0.0f;
    float phi = 0.63661977236758134308f * acv - 1.0f;    // 2/pi
    float ixf = ((theta + 1.0f)*256.0f - 1.0f)*0.5f;
    float iyf = ((phi   + 1.0f)*128.0f - 1.0f)*0.5f;
    float x0f = floorf(ixf), y0f = floorf(iyf);
    float wx = ixf - x0f, wy = iyf - y0f;
    v0 = 0.f; v1 = 0.f; v2 = 0.f;
    auto tap = [&](float xc, float yc, float w) {
        if (xc >= 0.0f && xc < 256.0f && yc >= 0.0f && yc < 128.0f) {
            int xi = (int)xc, yi = (int)yc;
            const float* e = env_map + yi*256 + xi;
            v0 += w * e[0];
            v1 += w * e[128*256];
            v2 += w * e[2*128*256];
        }
    };
    tap(x0f,      y0f,      (1.0f-wx)*(1.0f-wy));
    tap(x0f+1.0f, y0f,      wx*(1.0f-wy));
    tap(x0f,      y0f+1.0f, (1.0f-wx)*wy);
    tap(x0f+1.0f, y0f+1.0f, wx*wy);
}

// 256 threads/block = 1 ray; lane pair (2s,2s+1) shares sub-ray s.
// r16: scattered pool exported to global list, processed by pool_kernel.
// r17: cheap atan2/acos; pool kernel gets segmented-reduce atomics.
__global__ __launch_bounds__(256)
void render_kernel(const float* __restrict__ rays_o,
                   const float* __restrict__ rays_d,
                   const float* __restrict__ env_map,
                   const float* __restrict__ Wd1,
                   const float* __restrict__ Wd2,
                   const float* __restrict__ Wf1,
                   const float* __restrict__ Ws,
                   const float* __restrict__ Wdir,
                   const float* __restrict__ Wrho,
                   const float* __restrict__ jitter,
                   const float* __restrict__ u_t,
                   const float* __restrict__ u_scatter,
                   const int*   __restrict__ channel,
                   unsigned int* __restrict__ g_count,
                   float4* __restrict__ e0g,
                   float4* __restrict__ e1g,
                   float2* __restrict__ e2g,
                   int cap,
                   float* __restrict__ out)
{
    const int ray  = blockIdx.x;
    const int tid  = threadIdx.x;
    const int s    = tid >> 1;
    const int half = tid & 1;
    const int m    = ray * TOT + s;
    const int kbase = half * 8;

    __shared__ f32x4 sAB[HID];     // {A,A,B,B}
    __shared__ f32x4 sW01[HID];    // {w20,w20,w21,w21}
    __shared__ f32x2 sW2[HID];     // {w22,w22}
    __shared__ f32x4 sPW[HID];     // {pw1x,pw1y,pw1z,0}
    __shared__ f32x4 sM0[HID];     // {P, Q, ws0, ws1}
    __shared__ f32x4 sM1[HID];     // {ws2, wd0, wd1, wd2}
    __shared__ f32x4 sM2[HID];     // {wr0, wr1, wr2, 0}
    __shared__ float sT0[NTAB];
    __shared__ float sT1[NTAB];
    __shared__ float sT2[NTAB];
    __shared__ f32x4 sP0[TOT];     // pool: {ox,oy,oz,dx}
    __shared__ f32x4 sP1[TOT];     // pool: {dy,dz,thr0,thr1}
    __shared__ f32x2 sP2[TOT];     // pool: {thr2, (float)m}
    __shared__ float sEnvE[3];
    __shared__ int   sCnt;
    __shared__ int   sGbase;
    __shared__ float sred[4][3];

    // ---- prefetch per-thread globals (both jitter planes up front) ----
    const float4* j0p = (const float4*)(jitter + (size_t)m*INDS + kbase);
    float4 j0A = j0p[0], j0B = j0p[1];
    const float4* j1p = (const float4*)(jitter + ((size_t)MTOT + m)*INDS + kbase);
    float4 j1A = j1p[0], j1B = j1p[1];
    int   ch = channel[m];
    float ut = u_t[m];
    float us = u_scatter[m];

    float ox = rays_o[ray*3+0], oy = rays_o[ray*3+1], oz = rays_o[ray*3+2];
    float dx = rays_d[ray*3+0], dy = rays_d[ray*3+1], dz = rays_d[ray*3+2];

    if (tid == 0) sCnt = 0;
    // ---- per-block weight tables ----
    if (tid < HID) {
        const float INV2PI = 0.15915494309189535f;
        float w1x = Wd1[tid], w1y = Wd1[HID+tid], w1z = Wd1[2*HID+tid];
        float pw1x = w1x*INV2PI, pw1y = w1y*INV2PI, pw1z = w1z*INV2PI;
        float A = ox*pw1x + oy*pw1y + oz*pw1z;
        float B = dx*pw1x + dy*pw1y + dz*pw1z;
        float w20 = Wd2[3*tid], w21 = Wd2[3*tid+1], w22 = Wd2[3*tid+2];
        sAB[tid]  = (f32x4){A, A, B, B};
        sW01[tid] = (f32x4){w20, w20, w21, w21};
        sW2[tid]  = (f32x2){w22, w22};
        sPW[tid]  = (f32x4){pw1x, pw1y, pw1z, 0.0f};
        float f0 = Wf1[tid],       f1 = Wf1[HID+tid],   f2 = Wf1[2*HID+tid];
        float f3 = Wf1[3*HID+tid], f4 = Wf1[4*HID+tid], f5 = Wf1[5*HID+tid];
        float P = ox*f0 + oy*f1 + oz*f2 + dx*f3 + dy*f4 + dz*f5;
        float Q = dx*f0 + dy*f1 + dz*f2;
        sM0[tid] = (f32x4){P, Q, Ws[3*tid], Ws[3*tid+1]};
        sM1[tid] = (f32x4){Ws[3*tid+2], Wdir[3*tid], Wdir[3*tid+1], Wdir[3*tid+2]};
        sM2[tid] = (f32x4){Wrho[3*tid], Wrho[3*tid+1], Wrho[3*tid+2], 0.0f};
    }
    __syncthreads();

    // ---- block-uniform depth-0 geometry + density table + env ----
    float a0g = dx*dx + dy*dy + dz*dz;
    float b0g = 2.0f*(dx*ox + dy*oy + dz*oz);
    float c0g = (ox*ox + oy*oy + oz*oz) - 1.0f;
    float delta0 = b0g*b0g - 4.0f*a0g*c0g;
    bool alive = (delta0 > 0.0f);   // block-uniform

    float nears = 0.f, fars = 0.f, span = 0.f, ztab0 = 0.f, invh = 0.f;
    if (alive) {
        float sq = sqrtf(delta0);
        float inv2a = rcp_f(a0g + a0g);
        nears = fmaxf((-b0g - sq) * inv2a, 0.001f);
        fars  = fmaxf((-b0g + sq) * inv2a, 0.001f);
        span  = fars - nears;
        ztab0 = fmaf(-span, 0.03125f, nears);
        float width = span * 1.0625f;
        float hstep = width * (1.0f/(NTAB-1));
        invh = (float)(NTAB-1) * rcp_f(width);
        int p = tid >> 1;
        float zp = fmaf((float)p, hstep, ztab0);
        float f0 = 0.f, f1 = 0.f, f2 = 0.f;
        const int jb = half * 32;
        #pragma unroll 4
        for (int j = jb; j < jb + 32; ++j) {
            f32x4 ab  = sAB[j];
            f32x4 w01 = sW01[j];
            f32x2 w2  = sW2[j];
            float hv = __builtin_amdgcn_sinf(fmaf(zp, ab.z, ab.x));
            f0 = fmaf(hv, w01.x, f0);
            f1 = fmaf(hv, w01.z, f1);
            f2 = fmaf(hv, w2.x, f2);
        }
        f0 += __shfl_xor(f0, 1, 64);
        f1 += __shfl_xor(f1, 1, 64);
        f2 += __shfl_xor(f2, 1, 64);
        if (half == 0) { sT0[p] = f0; sT1[p] = f1; sT2[p] = f2; }
        if (tid == 0) {
            float v0,v1,v2;
            env_logv(env_map, fmaf(dx,fars,ox), fmaf(dy,fars,oy), fmaf(dz,fars,oz),
                     v0,v1,v2);
            sEnvE[0] = __expf(v0); sEnvE[1] = __expf(v1); sEnvE[2] = __expf(v2);
        }
    }
    __syncthreads();

    float thr0 = 1.f, thr1 = 1.f, thr2 = 1.f;
    float rgb0 = 0.f, rgb1 = 0.f, rgb2 = 0.f;
    bool  tab_d1 = false;
    float tadv = 0.f;

    // ================= depth 0 =================
    if (alive) {
        MAKE_Z(j0A, j0B, kbase, nears, span)
        float mx0 = -1e30f, mx1 = -1e30f, mx2 = -1e30f;
        TAB_EVAL(z01.x, mx0,mx1,mx2) TAB_EVAL(z01.y, mx0,mx1,mx2)
        TAB_EVAL(z23.x, mx0,mx1,mx2) TAB_EVAL(z23.y, mx0,mx1,mx2)
        TAB_EVAL(z45.x, mx0,mx1,mx2) TAB_EVAL(z45.y, mx0,mx1,mx2)
        TAB_EVAL(z67.x, mx0,mx1,mx2) TAB_EVAL(z67.y, mx0,mx1,mx2)
        mx0 = fmaxf(mx0, __shfl_xor(mx0, 1, 64));
        mx1 = fmaxf(mx1, __shfl_xor(mx1, 1, 64));
        mx2 = fmaxf(mx2, __shfl_xor(mx2, 1, 64));

        float maj0 = fmaxf(softplus_f(mx0), 0.001f);
        float maj1 = fmaxf(softplus_f(mx1), 0.001f);
        float maj2 = fmaxf(softplus_f(mx2), 0.001f);
        float mmax = fmaxf(fmaxf(maj0, maj1), maj2);

        float maj = (ch == 0) ? maj0 : ((ch == 1) ? maj1 : maj2);
        float t   = fmaf(-__logf(1.0f - ut), rcp_f(maj), nears);

        if (t >= fars) {
            float im   = rcp_f(mmax + EPSF);
            float den0 = fmaf(__expf(-maj0*span), im, EPSF);
            float den1 = fmaf(__expf(-maj1*span), im, EPSF);
            float den2 = fmaf(__expf(-maj2*span), im, EPSF);
            float idm = 3.0f * rcp_f(den0+den1+den2);
            rgb0 = den0*idm*sEnvE[0];
            rgb1 = den1*idm*sEnvE[1];
            rgb2 = den2*idm*sEnvE[2];
        } else {
            float tn  = t - nears;
            float imm = rcp_f(mmax);
            float tr0 = __expf(-maj0*tn) * imm;
            float tr1 = __expf(-maj1*tn) * imm;
            float tr2 = __expf(-maj2*tn) * imm;
            float i2m = 3.0f * rcp_f(maj0*tr0 + maj1*tr1 + maj2*tr2);
            thr0 = tr0 * i2m;
            thr1 = tr1 * i2m;
            thr2 = tr2 * i2m;
            ox = fmaf(dx, t, ox); oy = fmaf(dy, t, oy); oz = fmaf(dz, t, oz);

            // material MLP (DS-only; pre = P + t*Q)
            float st0=0.f, st1=0.f, st2=0.f;
            float dn0=0.f, dn1=0.f, dn2v=0.f;
            float rh0=0.f, rh1=0.f, rh2=0.f;
            const int j0 = half * 32;
            #pragma unroll 2
            for (int j = j0; j < j0 + 32; ++j) {
                f32x4 q0 = sM0[j];
                f32x4 q1 = sM1[j];
                f32x4 q2 = sM2[j];
                float pre = fmaf(t, q0.y, q0.x);
                float f = tanh_fast(pre);
                st0  = fmaf(f, q0.z, st0);
                st1  = fmaf(f, q0.w, st1);
                st2  = fmaf(f, q1.x, st2);
                dn0  = fmaf(f, q1.y, dn0);
                dn1  = fmaf(f, q1.z, dn1);
                dn2v = fmaf(f, q1.w, dn2v);
                rh0  = fmaf(f, q2.x, rh0);
                rh1  = fmaf(f, q2.y, rh1);
                rh2  = fmaf(f, q2.z, rh2);
            }
            st0  += __shfl_xor(st0, 1, 64);
            st1  += __shfl_xor(st1, 1, 64);
            st2  += __shfl_xor(st2, 1, 64);
            dn0  += __shfl_xor(dn0, 1, 64);
            dn1  += __shfl_xor(dn1, 1, 64);
            dn2v += __shfl_xor(dn2v, 1, 64);
            rh0  += __shfl_xor(rh0, 1, 64);
            rh1  += __shfl_xor(rh1, 1, 64);
            rh2  += __shfl_xor(rh2, 1, 64);

            float stch = (ch == 0) ? st0 : ((ch == 1) ? st1 : st2);
            float sp = fminf(softplus_f(stch) * rcp_f(maj), 1.0f);
            if (us < sp) {
                float inr = rcp_f(sqrtf(dn0*dn0 + dn1*dn1 + dn2v*dn2v) + EPSF);
                float ndx = dn0*inr, ndy = dn1*inr, ndz = dn2v*inr;
                float isp = rcp_f(sp + EPSF);
                float t0 = thr0 * isp * sigmoid_f(rh0);
                float t1 = thr1 * isp * sigmoid_f(rh1);
                float t2 = thr2 * isp * sigmoid_f(rh2);
                if (half == 0) {
                    int sl = atomicAdd(&sCnt, 1);
                    sP0[sl] = (f32x4){ox, oy, oz, ndx};
                    sP1[sl] = (f32x4){ndy, ndz, t0, t1};
                    sP2[sl] = (f32x2){t2, (float)m};
                }
            } else {
                float iv = rcp_f(1.0f - sp + EPSF);
                thr0 *= iv; thr1 *= iv; thr2 *= iv;
                tab_d1 = true;
                tadv = t;
            }
        }
    }
    __syncthreads();
    int npool = sCnt;

    // ---- export pool to global list (one atomic per block) ----
    if (tid == 0) {
        sGbase = (cap > 0 && npool > 0)
               ? (int)atomicAdd(g_count, (unsigned int)npool) : 0;
    }
    __syncthreads();
    int gbase = sGbase;
    for (int i = tid; i < npool; i += 256) {
        int gi = gbase + i;
        if (gi < cap) {
            f32x4 a = sP0[i]; f32x4 b = sP1[i]; f32x2 c = sP2[i];
            e0g[gi] = make_float4(a.x, a.y, a.z, a.w);
            e1g[gi] = make_float4(b.x, b.y, b.z, b.w);
            e2g[gi] = make_float2(c.x, c.y);
        }
    }
    int qstart = npool;
    if (cap > 0) {
        int fit = cap - gbase;
        if (fit < 0) fit = 0;
        if (fit > npool) fit = npool;
        qstart = fit;
    } else {
        qstart = 0;
    }

    // ===== depth 1, non-scattered: same line as depth 0, roots shift by -t
    if (tab_d1) {
        float fars1 = fmaxf(fars - tadv, 0.001f);
        float span1 = fars1 - 0.001f;
        float n1    = tadv + 0.001f;
        MAKE_Z(j1A, j1B, kbase, n1, span1)
        float mx0 = -1e30f, mx1 = -1e30f, mx2 = -1e30f;
        TAB_EVAL(z01.x, mx0,mx1,mx2) TAB_EVAL(z01.y, mx0,mx1,mx2)
        TAB_EVAL(z23.x, mx0,mx1,mx2) TAB_EVAL(z23.y, mx0,mx1,mx2)
        TAB_EVAL(z45.x, mx0,mx1,mx2) TAB_EVAL(z45.y, mx0,mx1,mx2)
        TAB_EVAL(z67.x, mx0,mx1,mx2) TAB_EVAL(z67.y, mx0,mx1,mx2)
        mx0 = fmaxf(mx0, __shfl_xor(mx0, 1, 64));
        mx1 = fmaxf(mx1, __shfl_xor(mx1, 1, 64));
        mx2 = fmaxf(mx2, __shfl_xor(mx2, 1, 64));

        float maj0 = fmaxf(softplus_f(mx0), 0.001f);
        float maj1 = fmaxf(softplus_f(mx1), 0.001f);
        float maj2 = fmaxf(softplus_f(mx2), 0.001f);
        float mmax = fmaxf(fmaxf(maj0, maj1), maj2);

        float im   = rcp_f(mmax + EPSF);
        float den0 = fmaf(__expf(-maj0*span1), im, EPSF);
        float den1 = fmaf(__expf(-maj1*span1), im, EPSF);
        float den2 = fmaf(__expf(-maj2*span1), im, EPSF);
        float idm = 3.0f * rcp_f(den0+den1+den2);
        rgb0 += thr0 * den0*idm*sEnvE[0];
        rgb1 += thr1 * den1*idm*sEnvE[1];
        rgb2 += thr2 * den2*idm*sEnvE[2];
    }

    // ===== depth 1, scattered OVERFLOW only (normally empty) =====
    {
        const int qlane = tid & 3;
        const int kq    = qlane * 4;
        const float kqf = (float)kq;
        for (int q = qstart + (tid >> 2); q < npool; q += 64) {
            f32x4 p0 = sP0[q];
            f32x4 p1 = sP1[q];
            f32x2 p2 = sP2[q];
            float pox = p0.x, poy = p0.y, poz = p0.z;
            float pdx = p0.w, pdy = p1.x, pdz = p1.y;
            float pt0 = p1.z, pt1 = p1.w, pt2 = p2.x;
            int   mm  = (int)p2.y;

            float a1 = pdx*pdx + pdy*pdy + pdz*pdz;
            float b1 = 2.0f*(pdx*pox + pdy*poy + pdz*poz);
            float c1 = (pox*pox + poy*poy + poz*poz) - 1.0f;
            float delta1 = b1*b1 - 4.0f*a1*c1;
            if (delta1 > 0.0f) {
                const float4* jp = (const float4*)(jitter + ((size_t)MTOT + mm)*INDS + kq);
                float4 jq = jp[0];
                float sq1    = sqrtf(delta1);
                float inv2a1 = rcp_f(a1 + a1);
                float nears1 = fmaxf((-b1 - sq1) * inv2a1, 0.001f);
                float fars1  = fmaxf((-b1 + sq1) * inv2a1, 0.001f);
                float span1  = fars1 - nears1;
                float s16q   = span1 * (1.0f/16.0f);
                f32x2 zA, zB;
                zA.x = fmaf(jq.x, s16q, fmaf(span1, (kqf+0.0f)*(1.0f/15.0f) - 0.03125f, nears1));
                zA.y = fmaf(jq.y, s16q, fmaf(span1, (kqf+1.0f)*(1.0f/15.0f) - 0.03125f, nears1));
                zB.x = fmaf(jq.z, s16q, fmaf(span1, (kqf+2.0f)*(1.0f/15.0f) - 0.03125f, nears1));
                zB.y = fmaf(jq.w, s16q, fmaf(span1, (kqf+3.0f)*(1.0f/15.0f) - 0.03125f, nears1));

                f32x2 a0A = {0.f,0.f}, a0B = {0.f,0.f};
                f32x2 a1A = {0.f,0.f}, a1B = {0.f,0.f};
                f32x2 a2A = {0.f,0.f}, a2B = {0.f,0.f};
                #pragma unroll 2
                for (int j = 0; j < HID; ++j) {
                    f32x4 pw  = sPW[j];
                    f32x4 w01 = sW01[j];
                    f32x2 w2  = sW2[j];
                    float A = fmaf(pox, pw.x, fmaf(poy, pw.y, poz*pw.z));
                    float B = fmaf(pdx, pw.x, fmaf(pdy, pw.y, pdz*pw.z));
                    f32x2 A2 = {A, A}, B2 = {B, B};
                    f32x2 gA = pkfma(zA, B2, A2);
                    f32x2 gB = pkfma(zB, B2, A2);
                    f32x2 hA, hB;
                    hA.x = __builtin_amdgcn_sinf(gA.x); hA.y = __builtin_amdgcn_sinf(gA.y);
                    hB.x = __builtin_amdgcn_sinf(gB.x); hB.y = __builtin_amdgcn_sinf(gB.y);
                    f32x2 W0 = {w01.x, w01.y}, W1 = {w01.z, w01.w};
                    a0A = pkfma(hA, W0, a0A); a0B = pkfma(hB, W0, a0B);
                    a1A = pkfma(hA, W1, a1A); a1B = pkfma(hB, W1, a1B);
                    a2A = pkfma(hA, w2, a2A); a2B = pkfma(hB, w2, a2B);
                }
                f32x2 pm0 = pkmax(a0A, a0B);
                f32x2 pm1 = pkmax(a1A, a1B);
                f32x2 pm2 = pkmax(a2A, a2B);
                float mx0 = fmaxf(pm0.x, pm0.y);
                float mx1 = fmaxf(pm1.x, pm1.y);
                float mx2 = fmaxf(pm2.x, pm2.y);
                mx0 = fmaxf(mx0, __shfl_xor(mx0, 1, 64));
                mx1 = fmaxf(mx1, __shfl_xor(mx1, 1, 64));
                mx2 = fmaxf(mx2, __shfl_xor(mx2, 1, 64));
                mx0 = fmaxf(mx0, __shfl_xor(mx0, 2, 64));
                mx1 = fmaxf(mx1, __shfl_xor(mx1, 2, 64));
                mx2 = fmaxf(mx2, __shfl_xor(mx2, 2, 64));

                float maj0 = fmaxf(softplus_f(mx0), 0.001f);
                float maj1 = fmaxf(softplus_f(mx1), 0.001f);
                float maj2 = fmaxf(softplus_f(mx2), 0.001f);
                float mmax = fmaxf(fmaxf(maj0, maj1), maj2);

                float im   = rcp_f(mmax + EPSF);
                float den0 = fmaf(__expf(-maj0*span1), im, EPSF);
                float den1 = fmaf(__expf(-maj1*span1), im, EPSF);
                float den2 = fmaf(__expf(-maj2*span1), im, EPSF);
                float idm = 3.0f * rcp_f(den0+den1+den2);
                float v0,v1,v2;
                env_logv(env_map, fmaf(pdx,fars1,pox), fmaf(pdy,fars1,poy),
                         fmaf(pdz,fars1,poz), v0,v1,v2);
                if (qlane < 2) {
                    rgb0 += pt0 * den0*idm*__expf(v0);
                    rgb1 += pt1 * den1*idm*__expf(v1);
                    rgb2 += pt2 * den2*idm*__expf(v2);
                }
            }
        }
    }

    // ---- reduction: each sub-ray counted x2 -> sum/256 == mean/128 ----
    float r0 = rgb0, r1 = rgb1, r2 = rgb2;
    #pragma unroll
    for (int off = 32; off > 0; off >>= 1) {
        r0 += __shfl_down(r0, off, 64);
        r1 += __shfl_down(r1, off, 64);
        r2 += __shfl_down(r2, off, 64);
    }
    int wave = tid >> 6;
    if ((tid & 63) == 0) {
        sred[wave][0] = r0; sred[wave][1] = r1; sred[wave][2] = r2;
    }
    __syncthreads();
    if (tid == 0) {
        out[ray*3+0] = (sred[0][0]+sred[1][0]+sred[2][0]+sred[3][0]) * (1.0f/256.0f);
        out[ray*3+1] = (sred[0][1]+sred[1][1]+sred[2][1]+sred[3][1]) * (1.0f/256.0f);
        out[ray*3+2] = (sred[0][2]+sred[1][2]+sred[2][2]+sred[3][2]) * (1.0f/256.0f);
    }
}

// Grid-strided, globally balanced scattered-pool pass, teams of 4.
// r17: (a) per-wave SEGMENTED REDUCE-BY-RAY over team leaders before the
// global atomicAdd -- entries are ray-contiguous runs, so keys within a
// wave are contiguous; reduces ~250k heavily-conflicting device atomics
// (16 lanes/instr on 1-2 addresses, 64B-line ping-pong across XCDs) to
// ~20k conflict-free ones. (b) first entry prefetched before the weight
// staging barrier. (c) unroll 4 on the MLP loop. (d) cheap env transcend.
__global__ __launch_bounds__(256)
void pool_kernel(const float* __restrict__ env_map,
                 const float* __restrict__ Wd1,
                 const float* __restrict__ Wd2,
                 const float* __restrict__ jitter,
                 const unsigned int* __restrict__ g_count,
                 const float4* __restrict__ e0g,
                 const float4* __restrict__ e1g,
                 const float2* __restrict__ e2g,
                 int cap,
                 float* __restrict__ out)
{
    __shared__ f32x4 sPW4[HID];   // {pwx, pwy, pwz, w20}
    __shared__ f32x2 sW22[HID];   // {w21, w22}
    const int tid  = threadIdx.x;
    const int lane = tid & 63;
    const int qlane = tid & 3;
    const int kq    = qlane * 4;
    const float kqf = (float)kq;

    // early: count + first-entry loads overlap the weight staging
    int count = (int)*g_count;
    if (count > cap) count = cap;
    const int stride = gridDim.x * 64;
    int idx = blockIdx.x*64 + (tid >> 2);
    bool have = (idx < count);
    float4 p0, p1; float2 p2;
    if (have) { p0 = e0g[idx]; p1 = e1g[idx]; p2 = e2g[idx]; }

    if (tid < HID) {
        const float INV2PI = 0.15915494309189535f;
        sPW4[tid] = (f32x4){Wd1[tid]*INV2PI, Wd1[HID+tid]*INV2PI,
                            Wd1[2*HID+tid]*INV2PI, Wd2[3*tid]};
        sW22[tid] = (f32x2){Wd2[3*tid+1], Wd2[3*tid+2]};
    }
    __syncthreads();

    while (__any(have)) {
        int   oray = -1;
        float c0 = 0.f, c1 = 0.f, c2 = 0.f;
        if (have) {
            float pox = p0.x, poy = p0.y, poz = p0.z;
            float pdx = p0.w, pdy = p1.x, pdz = p1.y;
            float pt0 = p1.z, pt1 = p1.w, pt2 = p2.x;
            int   mm  = (int)p2.y;
            oray = mm >> 7;   // mm / TOT
            // jitter gather issued early (independent of the quadratic)
            float4 jq = *(const float4*)(jitter + ((size_t)MTOT + mm)*INDS + kq);

            float a1 = pdx*pdx + pdy*pdy + pdz*pdz;
            float b1 = 2.0f*(pdx*pox + pdy*poy + pdz*poz);
            float c1q = (pox*pox + poy*poy + poz*poz) - 1.0f;
            float delta1 = b1*b1 - 4.0f*a1*c1q;
            if (delta1 > 0.0f) {   // origin inside sphere -> essentially always
                float sq1    = sqrtf(delta1);
                float inv2a1 = rcp_f(a1 + a1);
                float nears1 = fmaxf((-b1 - sq1) * inv2a1, 0.001f);
                float fars1  = fmaxf((-b1 + sq1) * inv2a1, 0.001f);
                float span1  = fars1 - nears1;
                float s16q   = span1 * (1.0f/16.0f);
                f32x2 zA, zB;
                zA.x = fmaf(jq.x, s16q, fmaf(span1, (kqf+0.0f)*(1.0f/15.0f) - 0.03125f, nears1));
                zA.y = fmaf(jq.y, s16q, fmaf(span1, (kqf+1.0f)*(1.0f/15.0f) - 0.03125f, nears1));
                zB.x = fmaf(jq.z, s16q, fmaf(span1, (kqf+2.0f)*(1.0f/15.0f) - 0.03125f, nears1));
                zB.y = fmaf(jq.w, s16q, fmaf(span1, (kqf+3.0f)*(1.0f/15.0f) - 0.03125f, nears1));

                f32x2 a0A = {0.f,0.f}, a0B = {0.f,0.f};
                f32x2 a1A = {0.f,0.f}, a1B = {0.f,0.f};
                f32x2 a2A = {0.f,0.f}, a2B = {0.f,0.f};
                #pragma unroll 4
                for (int j = 0; j < HID; ++j) {
                    f32x4 pw  = sPW4[j];
                    f32x2 w22 = sW22[j];
                    float A = fmaf(pox, pw.x, fmaf(poy, pw.y, poz*pw.z));
                    float B = fmaf(pdx, pw.x, fmaf(pdy, pw.y, pdz*pw.z));
                    f32x2 A2 = {A, A}, B2 = {B, B};
                    f32x2 gA = pkfma(zA, B2, A2);
                    f32x2 gB = pkfma(zB, B2, A2);
                    f32x2 hA, hB;
                    hA.x = __builtin_amdgcn_sinf(gA.x); hA.y = __builtin_amdgcn_sinf(gA.y);
                    hB.x = __builtin_amdgcn_sinf(gB.x); hB.y = __builtin_amdgcn_sinf(gB.y);
                    f32x2 W0 = {pw.w, pw.w}, W1 = {w22.x, w22.x}, W2v = {w22.y, w22.y};
                    a0A = pkfma(hA, W0, a0A); a0B = pkfma(hB, W0, a0B);
                    a1A = pkfma(hA, W1, a1A); a1B = pkfma(hB, W1, a1B);
                    a2A = pkfma(hA, W2v, a2A); a2B = pkfma(hB, W2v, a2B);
                }
                f32x2 pm0 = pkmax(a0A, a0B);
                f32x2 pm1 = pkmax(a1A, a1B);
                f32x2 pm2 = pkmax(a2A, a2B);
                float mx0 = fmaxf(pm0.x, pm0.y);
                float mx1 = fmaxf(pm1.x, pm1.y);
                float mx2 = fmaxf(pm2.x, pm2.y);
                mx0 = fmaxf(mx0, __shfl_xor(mx0, 1, 64));
                mx1 = fmaxf(mx1, __shfl_xor(mx1, 1, 64));
                mx2 = fmaxf(mx2, __shfl_xor(mx2, 1, 64));
                mx0 = fmaxf(mx0, __shfl_xor(mx0, 2, 64));
                mx1 = fmaxf(mx1, __shfl_xor(mx1, 2, 64));
                mx2 = fmaxf(mx2, __shfl_xor(mx2, 2, 64));

                float maj0 = fmaxf(softplus_f(mx0), 0.001f);
                float maj1 = fmaxf(softplus_f(mx1), 0.001f);
                float maj2 = fmaxf(softplus_f(mx2), 0.001f);
                float mmax = fmaxf(fmaxf(maj0, maj1), maj2);

                float im   = rcp_f(mmax + EPSF);
                float den0 = fmaf(__expf(-maj0*span1), im, EPSF);
                float den1 = fmaf(__expf(-maj1*span1), im, EPSF);
                float den2 = fmaf(__expf(-maj2*span1), im, EPSF);
                float idm = 3.0f * rcp_f(den0+den1+den2);
                float v0,v1,v2;
                env_logv(env_map, fmaf(pdx,fars1,pox), fmaf(pdy,fars1,poy),
                         fmaf(pdz,fars1,poz), v0,v1,v2);
                if (qlane == 0) {
                    c0 = pt0*den0*idm*__expf(v0)*(1.0f/128.0f);
                    c1 = pt1*den1*idm*__expf(v1)*(1.0f/128.0f);
                    c2 = pt2*den2*idm*__expf(v2)*(1.0f/128.0f);
                }
            }
        }

        // ---- wave-level segmented suffix-reduce over team leaders ----
        // leaders are lanes = 0 mod 4; keys (oray) are contiguous runs.
        #pragma unroll
        for (int off = 4; off < 64; off <<= 1) {
            int   rk = __shfl_down(oray, off, 64);
            float w0 = __shfl_down(c0, off, 64);
            float w1 = __shfl_down(c1, off, 64);
            float w2 = __shfl_down(c2, off, 64);
            bool ok = ((lane + off) < 64) && (rk == oray);
            if (ok) { c0 += w0; c1 += w1; c2 += w2; }
        }
        int rprev = __shfl_up(oray, 4, 64);
        bool head = (lane < 4) || (rprev != oray);
        if (qlane == 0 && head && oray >= 0) {
            atomicAdd(&out[oray*3+0], c0);
            atomicAdd(&out[oray*3+1], c1);
            atomicAdd(&out[oray*3+2], c2);
        }

        idx += stride;
        have = (idx < count);
        if (have) { p0 = e0g[idx]; p1 = e1g[idx]; p2 = e2g[idx]; }
    }
}

extern "C" void kernel_launch(void* const* d_in, const int* in_sizes, int n_in,
                              void* d_out, int out_size, void* d_ws, size_t ws_size,
                              hipStream_t stream) {
    const float* rays_o    = (const float*)d_in[0];
    const float* rays_d    = (const float*)d_in[1];
    const float* env_map   = (const float*)d_in[2];
    const float* Wd1       = (const float*)d_in[3];
    const float* Wd2       = (const float*)d_in[4];
    const float* Wf1       = (const float*)d_in[5];
    const float* Ws        = (const float*)d_in[6];
    const float* Wdir      = (const float*)d_in[7];
    const float* Wrho      = (const float*)d_in[8];
    const float* jitter    = (const float*)d_in[9];
    const float* u_t       = (const float*)d_in[10];
    const float* u_scatter = (const float*)d_in[11];
    const int*   channel   = (const int*)d_in[12];
    float* out = (float*)d_out;

    // workspace layout: [0..4) count | [256 ..) e0 | e1 | e2
    int cap = 0;
    unsigned int* g_count = nullptr;
    float4* e0g = nullptr; float4* e1g = nullptr; float2* e2g = nullptr;
    if (d_ws && ws_size >= 4096) {
        long c = ((long)ws_size - 256) / 40;   // 16+16+8 bytes per entry
        if (c > MTOT) c = MTOT;
        cap = (int)c;
        char* base = (char*)d_ws;
        g_count = (unsigned int*)base;
        e0g = (float4*)(base + 256);
        e1g = (float4*)(base + 256 + (size_t)cap*16);
        e2g = (float2*)(base + 256 + (size_t)cap*32);
    }

    if (cap > 0) {
        hipMemsetAsync(d_ws, 0, 4, stream);
    }

    render_kernel<<<dim3(NRAYS), dim3(256), 0, stream>>>(
        rays_o, rays_d, env_map, Wd1, Wd2, Wf1, Ws, Wdir, Wrho,
        jitter, u_t, u_scatter, channel,
        g_count, e0g, e1g, e2g, cap, out);

    if (cap > 0) {
        pool_kernel<<<dim3(POOL_GRID), dim3(256), 0, stream>>>(
            env_map, Wd1, Wd2, jitter, g_count, e0g, e1g, e2g, cap, out);
    }
}

// Round 4
// 160.614 us; speedup vs baseline: 1.2828x; 1.0311x over previous
//
#include <hip/hip_runtime.h>
#include <math.h>

#define NRAYS 2048
#define TOT   128
#define INDS  16
#define HID   64
#define EPSF  1e-8f
#define MTOT  (NRAYS*TOT)
#define NTAB  128

typedef float f32x2 __attribute__((ext_vector_type(2)));
typedef float f32x4 __attribute__((ext_vector_type(4)));

__device__ __forceinline__ float rcp_f(float x) {
    return __builtin_amdgcn_rcpf(x);   // v_rcp_f32, ~1 ulp; tolerance is 0.0625
}
__device__ __forceinline__ float softplus_f(float x) {
    return fmaxf(x, 0.0f) + __logf(1.0f + __expf(-fabsf(x)));
}
__device__ __forceinline__ float sigmoid_f(float x) {
    return rcp_f(1.0f + __expf(-x));
}
__device__ __forceinline__ float tanh_fast(float x) {
    float e2 = __expf(2.0f * x);
    return 1.0f - 2.0f * rcp_f(e2 + 1.0f);
}
__device__ __forceinline__ f32x2 pkmax(f32x2 a, f32x2 b) {
    f32x2 r; r.x = fmaxf(a.x, b.x); r.y = fmaxf(a.y, b.y); return r;
}
__device__ __forceinline__ f32x2 pkfma(f32x2 a, f32x2 b, f32x2 c) {
    return __builtin_elementwise_fma(a, b, c);
}

// ---- cheap transcendentals (replace ocml atan2f/acosf: each was a 30-50 op
// sequence incl. an IEEE divide; these are ~16/~8 ops, err <= 7e-5 rad ->
// texel-coord err ~3e-3 -> rgb err ~1e-3, way under 0.0625 tolerance).
// r16/r17 ablation: libm env was the dominant pool-phase cost. ----
__device__ __forceinline__ float atan_poly(float r) {
    float r2 = r*r;
    float p = -0.0117212f;
    p = fmaf(p, r2,  0.05265332f);
    p = fmaf(p, r2, -0.11643287f);
    p = fmaf(p, r2,  0.19354346f);
    p = fmaf(p, r2, -0.33262347f);
    p = fmaf(p, r2,  0.99997726f);
    return r * p;
}
__device__ __forceinline__ float atan2_fast(float y, float x) {
    float ay = fabsf(y), ax = fabsf(x);
    float mx = fmaxf(ay, ax), mn = fminf(ay, ax);
    float r  = mn * rcp_f(fmaxf(mx, 1e-30f));
    float t  = atan_poly(r);
    t = (ay > ax) ? (1.57079632679f - t) : t;
    t = (x < 0.0f) ? (3.14159265359f - t) : t;
    return (y < 0.0f) ? -t : t;          // atan2(0,0) -> 0 (matches nan_to_num)
}
__device__ __forceinline__ float acos_fast(float x) {
    // Hastings: acos(|x|) = sqrt(1-|x|)*poly, err <= 6.7e-5 rad
    float ax = fabsf(x);
    float p = -0.0187293f;
    p = fmaf(p, ax,  0.0742610f);
    p = fmaf(p, ax, -0.2121144f);
    p = fmaf(p, ax,  1.5707288f);
    float s = sqrtf(1.0f - ax) * p;
    return (x < 0.0f) ? (3.14159265359f - s) : s;
}

// z_k = fma(j_k, span/16, fma(span, k/15 - 1/32, nears))
#define CK(i) ((float)(i)*(1.0f/15.0f) - 0.03125f)

#define MAKE_Z(jA, jB, kbase, nears, span)                                    \
    float s16 = (span) * (1.0f/16.0f);                                        \
    f32x2 z01, z23, z45, z67;                                                 \
    z01.x = fmaf((jA).x, s16, fmaf(span, CK((kbase)+0), nears));              \
    z01.y = fmaf((jA).y, s16, fmaf(span, CK((kbase)+1), nears));              \
    z23.x = fmaf((jA).z, s16, fmaf(span, CK((kbase)+2), nears));              \
    z23.y = fmaf((jA).w, s16, fmaf(span, CK((kbase)+3), nears));              \
    z45.x = fmaf((jB).x, s16, fmaf(span, CK((kbase)+4), nears));              \
    z45.y = fmaf((jB).y, s16, fmaf(span, CK((kbase)+5), nears));              \
    z67.x = fmaf((jB).z, s16, fmaf(span, CK((kbase)+6), nears));              \
    z67.y = fmaf((jB).w, s16, fmaf(span, CK((kbase)+7), nears));

#define TAB_EVAL(zz, mx0, mx1, mx2)                                           \
    {                                                                         \
        float x = ((zz) - ztab0) * invh;                                      \
        x = fminf(fmaxf(x, 0.0f), (float)(NTAB-1) - 1e-3f);                   \
        int i = (int)x; float w = x - (float)i;                               \
        float ta0 = sT0[i], tb0 = sT0[i+1];                                   \
        float ta1 = sT1[i], tb1 = sT1[i+1];                                   \
        float ta2 = sT2[i], tb2 = sT2[i+1];                                   \
        mx0 = fmaxf(mx0, fmaf(w, tb0 - ta0, ta0));                            \
        mx1 = fmaxf(mx1, fmaf(w, tb1 - ta1, ta1));                            \
        mx2 = fmaxf(mx2, fmaf(w, tb2 - ta2, ta2));                            \
    }

__device__ __forceinline__ void env_logv(
    const float* __restrict__ env_map,
    float px, float py, float pz,
    float& v0, float& v1, float& v2)
{
    float theta = atan2_fast(px, -pz) * (1.0f/3.14159265358979323846f);
    float acv = (fabsf(py) <= 1.0f) ? acos_fast(py) : 0.0f;
    float phi = 0.63661977236758134308f * acv - 1.0f;    // 2/pi
    float ixf = ((theta + 1.0f)*256.0f - 1.0f)*0.5f;
    float iyf = ((phi   + 1.0f)*128.0f - 1.0f)*0.5f;
    float x0f = floorf(ixf), y0f = floorf(iyf);
    float wx = ixf - x0f, wy = iyf - y0f;
    v0 = 0.f; v1 = 0.f; v2 = 0.f;
    auto tap = [&](float xc, float yc, float w) {
        if (xc >= 0.0f && xc < 256.0f && yc >= 0.0f && yc < 128.0f) {
            int xi = (int)xc, yi = (int)yc;
            const float* e = env_map + yi*256 + xi;
            v0 += w * e[0];
            v1 += w * e[128*256];
            v2 += w * e[2*128*256];
        }
    };
    tap(x0f,      y0f,      (1.0f-wx)*(1.0f-wy));
    tap(x0f+1.0f, y0f,      wx*(1.0f-wy));
    tap(x0f,      y0f+1.0f, (1.0f-wx)*wy);
    tap(x0f+1.0f, y0f+1.0f, wx*wy);
}

// 256 threads/block = 1 ray; lane pair (2s,2s+1) shares sub-ray s.
// r15: single kernel, rcp_f, analytic depth-1 roots, jitter plane-1 prefetch.
// r16/r17 (global pool split) ABLATION RESULT: split costs more than it
// saves (export+memset+launch+atomics ~= 7 us GPU); the real pool cost was
// libm atan2f/acosf. r18 = r15 structure + fast env in the in-block pool
// (no atomics needed there: all entries belong to this block's ray) +
// jq gather hoisted above the quadratic + unroll 4 on the pool MLP.
__global__ __launch_bounds__(256)
void render_kernel(const float* __restrict__ rays_o,
                   const float* __restrict__ rays_d,
                   const float* __restrict__ env_map,
                   const float* __restrict__ Wd1,
                   const float* __restrict__ Wd2,
                   const float* __restrict__ Wf1,
                   const float* __restrict__ Ws,
                   const float* __restrict__ Wdir,
                   const float* __restrict__ Wrho,
                   const float* __restrict__ jitter,
                   const float* __restrict__ u_t,
                   const float* __restrict__ u_scatter,
                   const int*   __restrict__ channel,
                   float* __restrict__ out)
{
    const int ray  = blockIdx.x;
    const int tid  = threadIdx.x;
    const int s    = tid >> 1;
    const int half = tid & 1;
    const int m    = ray * TOT + s;
    const int kbase = half * 8;

    __shared__ f32x4 sAB[HID];     // {A,A,B,B}
    __shared__ f32x4 sW01[HID];    // {w20,w20,w21,w21}
    __shared__ f32x2 sW2[HID];     // {w22,w22}
    __shared__ f32x4 sPW[HID];     // {pw1x,pw1y,pw1z,0}
    __shared__ f32x4 sM0[HID];     // {P, Q, ws0, ws1}
    __shared__ f32x4 sM1[HID];     // {ws2, wd0, wd1, wd2}
    __shared__ f32x4 sM2[HID];     // {wr0, wr1, wr2, 0}
    __shared__ float sT0[NTAB];    // density table, channel 0 (4B stride)
    __shared__ float sT1[NTAB];
    __shared__ float sT2[NTAB];
    __shared__ f32x4 sP0[TOT];     // pool: {ox,oy,oz,dx}
    __shared__ f32x4 sP1[TOT];     // pool: {dy,dz,thr0,thr1}
    __shared__ f32x2 sP2[TOT];     // pool: {thr2, (float)m}
    __shared__ float sEnvE[3];     // exp(env) at block-uniform exit point
    __shared__ int   sCnt;
    __shared__ float sred[4][3];

    // ---- prefetch per-thread globals (both jitter planes up front) ----
    const float4* j0p = (const float4*)(jitter + (size_t)m*INDS + kbase);
    float4 j0A = j0p[0], j0B = j0p[1];
    const float4* j1p = (const float4*)(jitter + ((size_t)MTOT + m)*INDS + kbase);
    float4 j1A = j1p[0], j1B = j1p[1];
    int   ch = channel[m];
    float ut = u_t[m];
    float us = u_scatter[m];

    float ox = rays_o[ray*3+0], oy = rays_o[ray*3+1], oz = rays_o[ray*3+2];
    float dx = rays_d[ray*3+0], dy = rays_d[ray*3+1], dz = rays_d[ray*3+2];

    if (tid == 0) sCnt = 0;
    // ---- per-block weight tables ----
    if (tid < HID) {
        const float INV2PI = 0.15915494309189535f;
        float w1x = Wd1[tid], w1y = Wd1[HID+tid], w1z = Wd1[2*HID+tid];
        float pw1x = w1x*INV2PI, pw1y = w1y*INV2PI, pw1z = w1z*INV2PI;
        float A = ox*pw1x + oy*pw1y + oz*pw1z;
        float B = dx*pw1x + dy*pw1y + dz*pw1z;
        float w20 = Wd2[3*tid], w21 = Wd2[3*tid+1], w22 = Wd2[3*tid+2];
        sAB[tid]  = (f32x4){A, A, B, B};
        sW01[tid] = (f32x4){w20, w20, w21, w21};
        sW2[tid]  = (f32x2){w22, w22};
        sPW[tid]  = (f32x4){pw1x, pw1y, pw1z, 0.0f};
        float f0 = Wf1[tid],       f1 = Wf1[HID+tid],   f2 = Wf1[2*HID+tid];
        float f3 = Wf1[3*HID+tid], f4 = Wf1[4*HID+tid], f5 = Wf1[5*HID+tid];
        float P = ox*f0 + oy*f1 + oz*f2 + dx*f3 + dy*f4 + dz*f5;
        float Q = dx*f0 + dy*f1 + dz*f2;
        sM0[tid] = (f32x4){P, Q, Ws[3*tid], Ws[3*tid+1]};
        sM1[tid] = (f32x4){Ws[3*tid+2], Wdir[3*tid], Wdir[3*tid+1], Wdir[3*tid+2]};
        sM2[tid] = (f32x4){Wrho[3*tid], Wrho[3*tid+1], Wrho[3*tid+2], 0.0f};
    }
    __syncthreads();

    // ---- block-uniform depth-0 geometry + density table + env ----
    float a0g = dx*dx + dy*dy + dz*dz;
    float b0g = 2.0f*(dx*ox + dy*oy + dz*oz);
    float c0g = (ox*ox + oy*oy + oz*oz) - 1.0f;
    float delta0 = b0g*b0g - 4.0f*a0g*c0g;
    bool alive = (delta0 > 0.0f);   // block-uniform

    float nears = 0.f, fars = 0.f, span = 0.f, ztab0 = 0.f, invh = 0.f;
    if (alive) {
        float sq = sqrtf(delta0);
        float inv2a = rcp_f(a0g + a0g);
        nears = fmaxf((-b0g - sq) * inv2a, 0.001f);
        fars  = fmaxf((-b0g + sq) * inv2a, 0.001f);
        span  = fars - nears;
        ztab0 = fmaf(-span, 0.03125f, nears);
        float width = span * 1.0625f;
        float hstep = width * (1.0f/(NTAB-1));
        invh = (float)(NTAB-1) * rcp_f(width);
        int p = tid >> 1;
        float zp = fmaf((float)p, hstep, ztab0);
        float f0 = 0.f, f1 = 0.f, f2 = 0.f;
        const int jb = half * 32;
        #pragma unroll 4
        for (int j = jb; j < jb + 32; ++j) {
            f32x4 ab  = sAB[j];
            f32x4 w01 = sW01[j];
            f32x2 w2  = sW2[j];
            float hv = __builtin_amdgcn_sinf(fmaf(zp, ab.z, ab.x));
            f0 = fmaf(hv, w01.x, f0);
            f1 = fmaf(hv, w01.z, f1);
            f2 = fmaf(hv, w2.x, f2);
        }
        f0 += __shfl_xor(f0, 1, 64);
        f1 += __shfl_xor(f1, 1, 64);
        f2 += __shfl_xor(f2, 1, 64);
        if (half == 0) { sT0[p] = f0; sT1[p] = f1; sT2[p] = f2; }
        if (tid == 0) {
            float v0,v1,v2;
            env_logv(env_map, fmaf(dx,fars,ox), fmaf(dy,fars,oy), fmaf(dz,fars,oz),
                     v0,v1,v2);
            sEnvE[0] = __expf(v0); sEnvE[1] = __expf(v1); sEnvE[2] = __expf(v2);
        }
    }
    __syncthreads();

    float thr0 = 1.f, thr1 = 1.f, thr2 = 1.f;
    float rgb0 = 0.f, rgb1 = 0.f, rgb2 = 0.f;
    bool  tab_d1 = false;
    float tadv = 0.f;

    // ================= depth 0 =================
    if (alive) {
        MAKE_Z(j0A, j0B, kbase, nears, span)
        float mx0 = -1e30f, mx1 = -1e30f, mx2 = -1e30f;
        TAB_EVAL(z01.x, mx0,mx1,mx2) TAB_EVAL(z01.y, mx0,mx1,mx2)
        TAB_EVAL(z23.x, mx0,mx1,mx2) TAB_EVAL(z23.y, mx0,mx1,mx2)
        TAB_EVAL(z45.x, mx0,mx1,mx2) TAB_EVAL(z45.y, mx0,mx1,mx2)
        TAB_EVAL(z67.x, mx0,mx1,mx2) TAB_EVAL(z67.y, mx0,mx1,mx2)
        mx0 = fmaxf(mx0, __shfl_xor(mx0, 1, 64));
        mx1 = fmaxf(mx1, __shfl_xor(mx1, 1, 64));
        mx2 = fmaxf(mx2, __shfl_xor(mx2, 1, 64));

        float maj0 = fmaxf(softplus_f(mx0), 0.001f);
        float maj1 = fmaxf(softplus_f(mx1), 0.001f);
        float maj2 = fmaxf(softplus_f(mx2), 0.001f);
        float mmax = fmaxf(fmaxf(maj0, maj1), maj2);

        float maj = (ch == 0) ? maj0 : ((ch == 1) ? maj1 : maj2);
        float t   = fmaf(-__logf(1.0f - ut), rcp_f(maj), nears);

        if (t >= fars) {
            float im   = rcp_f(mmax + EPSF);
            float den0 = fmaf(__expf(-maj0*span), im, EPSF);
            float den1 = fmaf(__expf(-maj1*span), im, EPSF);
            float den2 = fmaf(__expf(-maj2*span), im, EPSF);
            float idm = 3.0f * rcp_f(den0+den1+den2);
            rgb0 = den0*idm*sEnvE[0];
            rgb1 = den1*idm*sEnvE[1];
            rgb2 = den2*idm*sEnvE[2];
        } else {
            float tn  = t - nears;
            float imm = rcp_f(mmax);
            float tr0 = __expf(-maj0*tn) * imm;
            float tr1 = __expf(-maj1*tn) * imm;
            float tr2 = __expf(-maj2*tn) * imm;
            float i2m = 3.0f * rcp_f(maj0*tr0 + maj1*tr1 + maj2*tr2);
            thr0 = tr0 * i2m;   // thr was 1
            thr1 = tr1 * i2m;
            thr2 = tr2 * i2m;
            ox = fmaf(dx, t, ox); oy = fmaf(dy, t, oy); oz = fmaf(dz, t, oz);

            // material MLP (DS-only; pre = P + t*Q)
            float st0=0.f, st1=0.f, st2=0.f;
            float dn0=0.f, dn1=0.f, dn2v=0.f;
            float rh0=0.f, rh1=0.f, rh2=0.f;
            const int j0 = half * 32;
            #pragma unroll 2
            for (int j = j0; j < j0 + 32; ++j) {
                f32x4 q0 = sM0[j];
                f32x4 q1 = sM1[j];
                f32x4 q2 = sM2[j];
                float pre = fmaf(t, q0.y, q0.x);
                float f = tanh_fast(pre);
                st0  = fmaf(f, q0.z, st0);
                st1  = fmaf(f, q0.w, st1);
                st2  = fmaf(f, q1.x, st2);
                dn0  = fmaf(f, q1.y, dn0);
                dn1  = fmaf(f, q1.z, dn1);
                dn2v = fmaf(f, q1.w, dn2v);
                rh0  = fmaf(f, q2.x, rh0);
                rh1  = fmaf(f, q2.y, rh1);
                rh2  = fmaf(f, q2.z, rh2);
            }
            st0  += __shfl_xor(st0, 1, 64);
            st1  += __shfl_xor(st1, 1, 64);
            st2  += __shfl_xor(st2, 1, 64);
            dn0  += __shfl_xor(dn0, 1, 64);
            dn1  += __shfl_xor(dn1, 1, 64);
            dn2v += __shfl_xor(dn2v, 1, 64);
            rh0  += __shfl_xor(rh0, 1, 64);
            rh1  += __shfl_xor(rh1, 1, 64);
            rh2  += __shfl_xor(rh2, 1, 64);

            float stch = (ch == 0) ? st0 : ((ch == 1) ? st1 : st2);
            float sp = fminf(softplus_f(stch) * rcp_f(maj), 1.0f);
            if (us < sp) {
                float inr = rcp_f(sqrtf(dn0*dn0 + dn1*dn1 + dn2v*dn2v) + EPSF);
                float ndx = dn0*inr, ndy = dn1*inr, ndz = dn2v*inr;
                float isp = rcp_f(sp + EPSF);
                float t0 = thr0 * isp * sigmoid_f(rh0);
                float t1 = thr1 * isp * sigmoid_f(rh1);
                float t2 = thr2 * isp * sigmoid_f(rh2);
                if (half == 0) {
                    int sl = atomicAdd(&sCnt, 1);
                    sP0[sl] = (f32x4){ox, oy, oz, ndx};
                    sP1[sl] = (f32x4){ndy, ndz, t0, t1};
                    sP2[sl] = (f32x2){t2, (float)m};
                }
            } else {
                float iv = rcp_f(1.0f - sp + EPSF);
                thr0 *= iv; thr1 *= iv; thr2 *= iv;
                tab_d1 = true;
                tadv = t;
            }
        }
    }
    __syncthreads();
    int npool = sCnt;

    // ===== depth 1, non-scattered: same line as depth 0, roots shift by -t:
    // nears1 = 0.001 (origin inside sphere), fars1 = fars - t.
    if (tab_d1) {
        float fars1 = fmaxf(fars - tadv, 0.001f);
        float span1 = fars1 - 0.001f;
        float n1    = tadv + 0.001f;
        MAKE_Z(j1A, j1B, kbase, n1, span1)
        float mx0 = -1e30f, mx1 = -1e30f, mx2 = -1e30f;
        TAB_EVAL(z01.x, mx0,mx1,mx2) TAB_EVAL(z01.y, mx0,mx1,mx2)
        TAB_EVAL(z23.x, mx0,mx1,mx2) TAB_EVAL(z23.y, mx0,mx1,mx2)
        TAB_EVAL(z45.x, mx0,mx1,mx2) TAB_EVAL(z45.y, mx0,mx1,mx2)
        TAB_EVAL(z67.x, mx0,mx1,mx2) TAB_EVAL(z67.y, mx0,mx1,mx2)
        mx0 = fmaxf(mx0, __shfl_xor(mx0, 1, 64));
        mx1 = fmaxf(mx1, __shfl_xor(mx1, 1, 64));
        mx2 = fmaxf(mx2, __shfl_xor(mx2, 1, 64));

        float maj0 = fmaxf(softplus_f(mx0), 0.001f);
        float maj1 = fmaxf(softplus_f(mx1), 0.001f);
        float maj2 = fmaxf(softplus_f(mx2), 0.001f);
        float mmax = fmaxf(fmaxf(maj0, maj1), maj2);

        float im   = rcp_f(mmax + EPSF);
        float den0 = fmaf(__expf(-maj0*span1), im, EPSF);
        float den1 = fmaf(__expf(-maj1*span1), im, EPSF);
        float den2 = fmaf(__expf(-maj2*span1), im, EPSF);
        float idm = 3.0f * rcp_f(den0+den1+den2);
        rgb0 += thr0 * den0*idm*sEnvE[0];
        rgb1 += thr1 * den1*idm*sEnvE[1];
        rgb2 += thr2 * den2*idm*sEnvE[2];
    }

    // ===== depth 1, scattered: compacted exact pass, TEAM-OF-4 =====
    {
        const int qlane = tid & 3;          // sample quarter
        const int kq    = qlane * 4;
        const float kqf = (float)kq;
        for (int q = tid >> 2; q < npool; q += 64) {
            f32x4 p0 = sP0[q];
            f32x4 p1 = sP1[q];
            f32x2 p2 = sP2[q];
            float pox = p0.x, poy = p0.y, poz = p0.z;
            float pdx = p0.w, pdy = p1.x, pdz = p1.y;
            float pt0 = p1.z, pt1 = p1.w, pt2 = p2.x;
            int   mm  = (int)p2.y;

            // jitter gather issued early (independent of the quadratic)
            const float4* jp = (const float4*)(jitter + ((size_t)MTOT + mm)*INDS + kq);
            float4 jq = jp[0];               // L2/L3-warm from the prefetch

            float a1 = pdx*pdx + pdy*pdy + pdz*pdz;
            float b1 = 2.0f*(pdx*pox + pdy*poy + pdz*poz);
            float c1 = (pox*pox + poy*poy + poz*poz) - 1.0f;
            float delta1 = b1*b1 - 4.0f*a1*c1;
            if (delta1 > 0.0f) {
                float sq1    = sqrtf(delta1);
                float inv2a1 = rcp_f(a1 + a1);
                float nears1 = fmaxf((-b1 - sq1) * inv2a1, 0.001f);
                float fars1  = fmaxf((-b1 + sq1) * inv2a1, 0.001f);
                float span1  = fars1 - nears1;
                float s16q   = span1 * (1.0f/16.0f);
                f32x2 zA, zB;
                zA.x = fmaf(jq.x, s16q, fmaf(span1, (kqf+0.0f)*(1.0f/15.0f) - 0.03125f, nears1));
                zA.y = fmaf(jq.y, s16q, fmaf(span1, (kqf+1.0f)*(1.0f/15.0f) - 0.03125f, nears1));
                zB.x = fmaf(jq.z, s16q, fmaf(span1, (kqf+2.0f)*(1.0f/15.0f) - 0.03125f, nears1));
                zB.y = fmaf(jq.w, s16q, fmaf(span1, (kqf+3.0f)*(1.0f/15.0f) - 0.03125f, nears1));

                f32x2 a0A = {0.f,0.f}, a0B = {0.f,0.f};
                f32x2 a1A = {0.f,0.f}, a1B = {0.f,0.f};
                f32x2 a2A = {0.f,0.f}, a2B = {0.f,0.f};
                #pragma unroll 4
                for (int j = 0; j < HID; ++j) {
                    f32x4 pw  = sPW[j];
                    f32x4 w01 = sW01[j];
                    f32x2 w2  = sW2[j];
                    float A = fmaf(pox, pw.x, fmaf(poy, pw.y, poz*pw.z));
                    float B = fmaf(pdx, pw.x, fmaf(pdy, pw.y, pdz*pw.z));
                    f32x2 A2 = {A, A}, B2 = {B, B};
                    f32x2 gA = pkfma(zA, B2, A2);
                    f32x2 gB = pkfma(zB, B2, A2);
                    f32x2 hA, hB;
                    hA.x = __builtin_amdgcn_sinf(gA.x); hA.y = __builtin_amdgcn_sinf(gA.y);
                    hB.x = __builtin_amdgcn_sinf(gB.x); hB.y = __builtin_amdgcn_sinf(gB.y);
                    f32x2 W0 = {w01.x, w01.y}, W1 = {w01.z, w01.w};
                    a0A = pkfma(hA, W0, a0A); a0B = pkfma(hB, W0, a0B);
                    a1A = pkfma(hA, W1, a1A); a1B = pkfma(hB, W1, a1B);
                    a2A = pkfma(hA, w2, a2A); a2B = pkfma(hB, w2, a2B);
                }
                f32x2 pm0 = pkmax(a0A, a0B);
                f32x2 pm1 = pkmax(a1A, a1B);
                f32x2 pm2 = pkmax(a2A, a2B);
                float mx0 = fmaxf(pm0.x, pm0.y);
                float mx1 = fmaxf(pm1.x, pm1.y);
                float mx2 = fmaxf(pm2.x, pm2.y);
                mx0 = fmaxf(mx0, __shfl_xor(mx0, 1, 64));
                mx1 = fmaxf(mx1, __shfl_xor(mx1, 1, 64));
                mx2 = fmaxf(mx2, __shfl_xor(mx2, 1, 64));
                mx0 = fmaxf(mx0, __shfl_xor(mx0, 2, 64));
                mx1 = fmaxf(mx1, __shfl_xor(mx1, 2, 64));
                mx2 = fmaxf(mx2, __shfl_xor(mx2, 2, 64));

                float maj0 = fmaxf(softplus_f(mx0), 0.001f);
                float maj1 = fmaxf(softplus_f(mx1), 0.001f);
                float maj2 = fmaxf(softplus_f(mx2), 0.001f);
                float mmax = fmaxf(fmaxf(maj0, maj1), maj2);

                float im   = rcp_f(mmax + EPSF);
                float den0 = fmaf(__expf(-maj0*span1), im, EPSF);
                float den1 = fmaf(__expf(-maj1*span1), im, EPSF);
                float den2 = fmaf(__expf(-maj2*span1), im, EPSF);
                float idm = 3.0f * rcp_f(den0+den1+den2);
                float v0,v1,v2;
                env_logv(env_map, fmaf(pdx,fars1,pox), fmaf(pdy,fars1,poy),
                         fmaf(pdz,fars1,poz), v0,v1,v2);
                if (qlane < 2) {
                    rgb0 += pt0 * den0*idm*__expf(v0);
                    rgb1 += pt1 * den1*idm*__expf(v1);
                    rgb2 += pt2 * den2*idm*__expf(v2);
                }
            }
        }
    }

    // ---- reduction: each sub-ray counted x2 -> sum/256 == mean/128 ----
    float r0 = rgb0, r1 = rgb1, r2 = rgb2;
    #pragma unroll
    for (int off = 32; off > 0; off >>= 1) {
        r0 += __shfl_down(r0, off, 64);
        r1 += __shfl_down(r1, off, 64);
        r2 += __shfl_down(r2, off, 64);
    }
    int wave = tid >> 6;
    if ((tid & 63) == 0) {
        sred[wave][0] = r0; sred[wave][1] = r1; sred[wave][2] = r2;
    }
    __syncthreads();
    if (tid == 0) {
        out[ray*3+0] = (sred[0][0]+sred[1][0]+sred[2][0]+sred[3][0]) * (1.0f/256.0f);
        out[ray*3+1] = (sred[0][1]+sred[1][1]+sred[2][1]+sred[3][1]) * (1.0f/256.0f);
        out[ray*3+2] = (sred[0][2]+sred[1][2]+sred[2][2]+sred[3][2]) * (1.0f/256.0f);
    }
}

extern "C" void kernel_launch(void* const* d_in, const int* in_sizes, int n_in,
                              void* d_out, int out_size, void* d_ws, size_t ws_size,
                              hipStream_t stream) {
    const float* rays_o    = (const float*)d_in[0];
    const float* rays_d    = (const float*)d_in[1];
    const float* env_map   = (const float*)d_in[2];
    const float* Wd1       = (const float*)d_in[3];
    const float* Wd2       = (const float*)d_in[4];
    const float* Wf1       = (const float*)d_in[5];
    const float* Ws        = (const float*)d_in[6];
    const float* Wdir      = (const float*)d_in[7];
    const float* Wrho      = (const float*)d_in[8];
    const float* jitter    = (const float*)d_in[9];
    const float* u_t       = (const float*)d_in[10];
    const float* u_scatter = (const float*)d_in[11];
    const int*   channel   = (const int*)d_in[12];
    float* out = (float*)d_out;

    render_kernel<<<dim3(NRAYS), dim3(256), 0, stream>>>(
        rays_o, rays_d, env_map, Wd1, Wd2, Wf1, Ws, Wdir, Wrho,
        jitter, u_t, u_scatter, channel, out);
}